// Round 9
// baseline (693.493 us; speedup 1.0000x reference)
//
#include <hip/hip_runtime.h>
#include <hip/hip_bf16.h>
#include <math.h>

// ---------- types ----------
typedef __attribute__((ext_vector_type(8)))  __bf16 bfrag;   // MFMA A/B operand (8 bf16)
typedef __attribute__((ext_vector_type(4)))  float  f32x4;
typedef __attribute__((ext_vector_type(16))) float  f32x16;  // 32x32 MFMA C/D
typedef __attribute__((ext_vector_type(8)))  short  s16x8;
typedef __attribute__((ext_vector_type(4)))  short  s16x4;
typedef __attribute__((ext_vector_type(2)))  unsigned u32x2;
typedef __attribute__((ext_vector_type(4)))  unsigned u32x4;

__device__ __forceinline__ short f2bf(float f) {
  return (short)__builtin_bit_cast(unsigned short, (__bf16)f);
}
__device__ __forceinline__ float bf2f(short s) {
  return (float)__builtin_bit_cast(__bf16, (unsigned short)s);
}
__device__ __forceinline__ unsigned cvtpk(float lo, float hi_) {
  unsigned r;
  asm("v_cvt_pk_bf16_f32 %0, %1, %2" : "=v"(r) : "v"(lo), "v"(hi_));
  return r;
}
__device__ __forceinline__ void gll16(const void* g, void* l) {
  __builtin_amdgcn_global_load_lds((const __attribute__((address_space(1))) void*)g,
                                   (__attribute__((address_space(3))) void*)l, 16, 0, 0);
}

// ---------- f32 -> bf16 converts ----------
__global__ __launch_bounds__(256) void cvt_f32_bf16(const float* __restrict__ in,
                                                    short* __restrict__ out, int n4) {
  int i = blockIdx.x * 256 + threadIdx.x;
  if (i >= n4) return;
  f32x4 v = ((const f32x4*)in)[i];
  s16x4 o;
  o.x = f2bf(v.x); o.y = f2bf(v.y); o.z = f2bf(v.z); o.w = f2bf(v.w);
  ((s16x4*)out)[i] = o;
}

// merged x|wq|wk|wv convert (one launch, 40960 blocks)
__global__ __launch_bounds__(256) void cvt4(const float* __restrict__ x,
                                            const float* __restrict__ wq,
                                            const float* __restrict__ wk,
                                            const float* __restrict__ wv,
                                            short* __restrict__ xb,
                                            short* __restrict__ wqb,
                                            short* __restrict__ wkb,
                                            short* __restrict__ wvb) {
  const int b = blockIdx.x;
  const float* in; short* out; int base;
  if (b < 16384)      { in = x;  out = xb;  base = 0; }
  else if (b < 32768) { in = wq; out = wqb; base = 16384 * 256; }
  else if (b < 36864) { in = wk; out = wkb; base = 32768 * 256; }
  else                { in = wv; out = wvb; base = 36864 * 256; }
  const int idx = b * 256 + threadIdx.x - base;
  f32x4 v = ((const f32x4*)in)[idx];
  s16x4 o;
  o.x = f2bf(v.x); o.y = f2bf(v.y); o.z = f2bf(v.z); o.w = f2bf(v.w);
  ((s16x4*)out)[idx] = o;
}

// ---------- GEMM 128x256, BK=64, 32x32x16 MFMA, 1-phase deep-prefetch ----------
// C[M][N] = A[M][K] @ B[N][K]^T, bf16 in. 8 waves (2M x 4N), per-wave 64x64 =
// 2x2 frags of 32x32. Per K-tile (ONE phase):
//   {16 ds_read_b128; lgkmcnt(0); barrier; STAGE kt+2 (6 gll16); 16 MFMA;
//    vmcnt(6); barrier}
// Deep prefetch: all stages target kt+2 -> each load has a FULL K-tile
// (~500-700cy) before its forced drain (vs 1 phase in prior rounds == the
// ~35% stall). WAR: bar#1 after lgkm(0) ensures all waves drained buf[p]
// before kt+2's DMA (same parity) can land. RAW: at boundary, outstanding =
// kt+1(6) + kt+2(6); vmcnt(6) drains exactly kt+1; bar#2 makes it global.
// 32x32x16 frag layout (verified in fattn2): A row=l31, k=ks*16+hi*8+j;
// C/D row=(r&3)+8*(r>>2)+4*hi, col=l31.
template<bool BF16OUT>
__global__ __launch_bounds__(512) void gemm32k(const short* __restrict__ A,
                                               const short* __restrict__ B,
                                               void* __restrict__ Cv,
                                               int M, int N, int K, int NBX) {
  __shared__ __align__(16) short As[2][128 * 64];   // 2 x 16 KB
  __shared__ __align__(16) short Bs[2][256 * 64];   // 2 x 32 KB (total 96 KB)
  const int tid = threadIdx.x, lane = tid & 63, wid = tid >> 6;
  const int l31 = lane & 31, hi = lane >> 5;
  const int wm = wid >> 2, wn = wid & 3;
  // bijective XCD-aware block swizzle (m204)
  const int nwg = gridDim.x, orig = blockIdx.x;
  const int qq = nwg >> 3, rr = nwg & 7, xc = orig & 7, o8 = orig >> 3;
  const int wg = (xc < rr ? xc * (qq + 1) : rr * (qq + 1) + (xc - rr) * qq) + o8;
  const int bm = (wg / NBX) << 7, bn = (wg % NBX) << 8;
  const int NT = K >> 6;
  // staging: unit = 128 rows x 64 cols = 2 x (512 thr x 16B)
  const int r0 = tid >> 3;                 // row within 64-row stripe
  const int c0 = tid & 7;
  const int csrc = c0 ^ (r0 & 7);          // inverse-swizzled 16B source chunk

#define STG(OP, OPs, boff, bb, hh, kt_)                                          \
  do {                                                                           \
    _Pragma("unroll")                                                            \
    for (int s = 0; s < 2; ++s)                                                  \
      gll16(OP + (size_t)(boff + (hh) * 128 + s * 64 + r0) * K + (kt_) * 64 + csrc * 8, \
            (char*)OPs[bb] + ((hh) * 128 + s * 64 + wid * 8) * 128);             \
  } while (0)
#define STG_TILE(bb, kt_)                                                        \
  do {                                                                           \
    STG(A, As, bm, bb, 0, kt_);                                                  \
    STG(B, Bs, bn, bb, 0, kt_);                                                  \
    STG(B, Bs, bn, bb, 1, kt_);                                                  \
  } while (0)

  // frag read offsets: k-step ks -> byte (ks*32 + hi*16) ^ ((l31&7)<<4)
  const int swz = (l31 & 7) << 4;
  int ko[4];
#pragma unroll
  for (int ks = 0; ks < 4; ++ks) ko[ks] = (ks * 32 + hi * 16) ^ swz;
  const int aoff = (wm * 64 + l31) * 128;   // A LDS byte base (row stride 128B)
  const int boff = (wn * 64 + l31) * 128;   // B LDS byte base

  // ---- prologue: tile0 -> buf0, tile1 -> buf1 ----
  STG_TILE(0, 0);
  if (NT > 1) {
    STG_TILE(1, 1);
    asm volatile("s_waitcnt vmcnt(6)" ::: "memory");   // tile0 landed
  } else {
    asm volatile("s_waitcnt vmcnt(0)" ::: "memory");
  }
  __builtin_amdgcn_s_barrier();
  __builtin_amdgcn_sched_barrier(0);

  f32x16 acc[2][2] = {};
  bfrag a_[2][4], b_[2][4];

  for (int kt = 0; kt < NT; ++kt) {
    const int p = kt & 1;
    // ---- read all fragments for this K-tile (16 x ds_read_b128) ----
    const char* Ab = (const char*)As[p] + aoff;
    const char* Bb = (const char*)Bs[p] + boff;
#pragma unroll
    for (int mt = 0; mt < 2; ++mt)
#pragma unroll
      for (int ks = 0; ks < 4; ++ks)
        a_[mt][ks] = *(const bfrag*)(Ab + mt * 4096 + ko[ks]);
#pragma unroll
    for (int nt = 0; nt < 2; ++nt)
#pragma unroll
      for (int ks = 0; ks < 4; ++ks)
        b_[nt][ks] = *(const bfrag*)(Bb + nt * 4096 + ko[ks]);
    asm volatile("s_waitcnt lgkmcnt(0)" ::: "memory");  // my reads of buf[p] done
    __builtin_amdgcn_s_barrier();                       // ALL waves' reads done
    __builtin_amdgcn_sched_barrier(0);
    // ---- stage kt+2 into buf[p] (now WAR-safe) ----
    if (kt + 2 < NT) STG_TILE(p, kt + 2);
    // ---- 16 x mfma_32x32x16 (2x FLOP/instr, frags in regs) ----
    __builtin_amdgcn_s_setprio(1);
#pragma unroll
    for (int ks = 0; ks < 4; ++ks)
#pragma unroll
      for (int mt = 0; mt < 2; ++mt)
#pragma unroll
        for (int nt = 0; nt < 2; ++nt)
          acc[mt][nt] = __builtin_amdgcn_mfma_f32_32x32x16_bf16(
              a_[mt][ks], b_[nt][ks], acc[mt][nt], 0, 0, 0);
    __builtin_amdgcn_s_setprio(0);
    // ---- boundary: kt+1 fully landed; kt+2 stays in flight ----
    if (kt + 1 < NT) {
      if (kt + 2 < NT) asm volatile("s_waitcnt vmcnt(6)" ::: "memory");
      else             asm volatile("s_waitcnt vmcnt(0)" ::: "memory");
      __builtin_amdgcn_s_barrier();
      __builtin_amdgcn_sched_barrier(0);
    }
  }
#undef STG
#undef STG_TILE
  // ---- epilogue: C/D layout row=(r&3)+8*(r>>2)+4*hi, col=l31 ----
  const int rb = bm + wm * 64 + 4 * hi, cb = bn + wn * 64 + l31;
#pragma unroll
  for (int mt = 0; mt < 2; ++mt)
#pragma unroll
    for (int nt = 0; nt < 2; ++nt)
#pragma unroll
      for (int r = 0; r < 16; ++r) {
        const int row = rb + mt * 32 + (r & 3) + 8 * (r >> 2);
        size_t idx = (size_t)row * N + (cb + nt * 32);
        if (BF16OUT) ((short*)Cv)[idx] = f2bf(acc[mt][nt][r]);
        else         ((float*)Cv)[idx] = acc[mt][nt][r];
      }
}

// ---------- RoPE in-place (q heads 0..31, k heads 32..39) ----------
__global__ __launch_bounds__(256) void rope_k(short* __restrict__ qkv,
                                              const float* __restrict__ fcos,
                                              const float* __restrict__ fsin) {
  const int t = blockIdx.x;
  const int s = t & 2047;
  unsigned* row = (unsigned*)(qkv + (size_t)t * 6144);
  for (int p = threadIdx.x; p < 2560; p += 256) {
    const int h = p >> 6, i = p & 63;
    const int w = h * 64 + i;
    unsigned u = row[w];
    float a  = bf2f((short)(u & 0xffff));
    float b  = bf2f((short)(u >> 16));
    float c  = fcos[s * 64 + i], sn = fsin[s * 64 + i];
    float na = a * c - b * sn;
    float nb = a * sn + b * c;
    row[w] = ((unsigned)(unsigned short)f2bf(na)) |
             (((unsigned)(unsigned short)f2bf(nb)) << 16);
  }
}

// ---------- V transpose: qkv V-part [t][d] -> vt[b][kvh][d][s] ----------
__global__ __launch_bounds__(256) void vtrans(const short* __restrict__ qkv,
                                              short* __restrict__ vt) {
  const int sb = blockIdx.x, kvh = blockIdx.y, b = blockIdx.z;
  __shared__ short T[64][136];
  const int tid = threadIdx.x;
#pragma unroll
  for (int it = 0; it < 4; ++it) {
    int c = it * 256 + tid;
    int r = c >> 4, dc = c & 15;
    s16x8 v = *(const s16x8*)(qkv + (size_t)(b * 2048 + sb * 64 + r) * 6144
                              + 5120 + kvh * 128 + dc * 8);
    *(s16x8*)&T[r][dc * 8] = v;
  }
  __syncthreads();
#pragma unroll
  for (int it = 0; it < 4; ++it) {
    int c = it * 256 + tid;
    int d = c >> 3, sc = c & 7;
    s16x8 v;
#pragma unroll
    for (int j = 0; j < 8; ++j) v[j] = T[sc * 8 + j][d];
    *(s16x8*)(vt + (size_t)((b * 8 + kvh) * 128 + d) * 2048 + sb * 64 + sc * 8) = v;
  }
}

// ---------- Flash attention, m214 structure; QK chains interleaved ----------
__global__ __launch_bounds__(512, 2) void fattn2(const short* __restrict__ qkv,
                                                 const short* __restrict__ vt,
                                                 short* __restrict__ ao) {
  const int qb = blockIdx.x, h = blockIdx.y, b = blockIdx.z;
  const int kvh = h >> 2;
  const int tid = threadIdx.x;
  const int lane = tid & 63, wid = tid >> 6;
  const int l31 = lane & 31, hi = lane >> 5;
  __shared__ __align__(16) short Ks[2][64 * 128];
  __shared__ __align__(16) short Vs[2][128 * 64];

  const int q0w   = qb * 256 + wid * 32;
  const int qg    = q0w + l31;
  const int tmaxw = q0w >> 6;
  const int NT    = 4 * qb + 4;

  bfrag qf[8];
  {
    const short* qp = qkv + (size_t)(b * 2048 + qg) * 6144 + h * 128 + hi * 8;
#pragma unroll
    for (int kk = 0; kk < 8; ++kk) qf[kk] = *(const bfrag*)(qp + kk * 16);
  }

  const int kr0 = tid >> 4, kcc = tid & 15;
  const int vd0 = tid >> 3, vkc = tid & 7;
  const int kro[2] = { kr0, kr0 + 32 };
  const int vdo[2] = { vd0, vd0 + 64 };
  int kldst[2], vldst[2];
#pragma unroll
  for (int i = 0; i < 2; ++i) {
    kldst[i] = (kro[i] * 256 + kcc * 16) ^ ((kro[i] & 7) << 4);
    vldst[i] = (vdo[i] * 128 + vkc * 16) ^ ((vdo[i] & 7) << 4);
  }
  const short* base_k = qkv + (size_t)(b * 2048) * 6144 + 4096 + kvh * 128;
  const short* base_v = vt + (size_t)((b * 8 + kvh) * 128) * 2048;

  {
    s16x8 kr_[2], vr_[2];
#pragma unroll
    for (int i = 0; i < 2; ++i) {
      kr_[i] = *(const s16x8*)(base_k + (size_t)kro[i] * 6144 + kcc * 8);
      vr_[i] = *(const s16x8*)(base_v + (size_t)vdo[i] * 2048 + vkc * 8);
    }
#pragma unroll
    for (int i = 0; i < 2; ++i) {
      *(s16x8*)((char*)Ks[0] + kldst[i]) = kr_[i];
      *(s16x8*)((char*)Vs[0] + vldst[i]) = vr_[i];
    }
  }
  __syncthreads();

  f32x16 o[4] = {};
  float m = -3.0e38f, l = 0.f;
  const float c0 = 0.08838834764831845f * 1.4426950408889634f;
  const int  sw = (l31 & 7) << 4;

  for (int t = 0; t < NT; ++t) {
    const int cur = t & 1;
    s16x8 kr_[2], vr_[2];
    const bool pf = (t + 1 < NT);
    if (pf) {
#pragma unroll
      for (int i = 0; i < 2; ++i) {
        kr_[i] = *(const s16x8*)(base_k + (size_t)((t + 1) * 64 + kro[i]) * 6144 + kcc * 8);
        vr_[i] = *(const s16x8*)(base_v + (size_t)vdo[i] * 2048 + (t + 1) * 64 + vkc * 8);
      }
    }
    if (t <= tmaxw) {
      // ---- S^T = K @ Q : two chains interleaved (kk outer) ----
      f32x16 st[2] = {};
      {
        const char* kb = (const char*)Ks[cur] + l31 * 256;
        __builtin_amdgcn_s_setprio(1);
#pragma unroll
        for (int kk = 0; kk < 8; ++kk) {
          const int ko = (kk * 32 + hi * 16) ^ sw;
          bfrag kf0 = *(const bfrag*)(kb + ko);
          bfrag kf1 = *(const bfrag*)(kb + 8192 + ko);
          st[0] = __builtin_amdgcn_mfma_f32_32x32x16_bf16(kf0, qf[kk], st[0], 0, 0, 0);
          st[1] = __builtin_amdgcn_mfma_f32_32x32x16_bf16(kf1, qf[kk], st[1], 0, 0, 0);
        }
        __builtin_amdgcn_s_setprio(0);
      }
      if (t == tmaxw) {
        const int kb0 = t * 64 + 4 * hi;
#pragma unroll
        for (int kt = 0; kt < 2; ++kt)
#pragma unroll
          for (int r = 0; r < 16; ++r) {
            int k = kb0 + kt * 32 + (r & 3) + 8 * (r >> 2);
            if (k > qg) st[kt][r] = -3.0e38f;
          }
      }
      float mt = -3.0e38f;
#pragma unroll
      for (int kt = 0; kt < 2; ++kt)
#pragma unroll
        for (int r = 0; r < 16; ++r) mt = fmaxf(mt, st[kt][r]);
      mt = fmaxf(mt, __shfl_xor(mt, 32, 64));
      if (!__all((mt - m) * c0 <= 8.0f)) {
        float nm = fmaxf(m, mt);
        float fe = exp2f((m - nm) * c0);
        m = nm;
        l *= fe;
#pragma unroll
        for (int dt = 0; dt < 4; ++dt)
#pragma unroll
          for (int r = 0; r < 16; ++r) o[dt][r] *= fe;
      }
      const float mc = m * c0;
      float ps = 0.f;
#pragma unroll
      for (int kt = 0; kt < 2; ++kt)
#pragma unroll
        for (int r = 0; r < 16; ++r) {
          float p = exp2f(st[kt][r] * c0 - mc);
          st[kt][r] = p;
          ps += p;
        }
      ps += __shfl_xor(ps, 32, 64);
      l += ps;
      bfrag pfr[4];
#pragma unroll
      for (int kt = 0; kt < 2; ++kt) {
        u32x2 a0 = __builtin_amdgcn_permlane32_swap(cvtpk(st[kt][0],  st[kt][1]),
                                                    cvtpk(st[kt][4],  st[kt][5]),  0, 0);
        u32x2 a1 = __builtin_amdgcn_permlane32_swap(cvtpk(st[kt][2],  st[kt][3]),
                                                    cvtpk(st[kt][6],  st[kt][7]),  0, 0);
        u32x2 b0 = __builtin_amdgcn_permlane32_swap(cvtpk(st[kt][8],  st[kt][9]),
                                                    cvtpk(st[kt][12], st[kt][13]), 0, 0);
        u32x2 b1 = __builtin_amdgcn_permlane32_swap(cvtpk(st[kt][10], st[kt][11]),
                                                    cvtpk(st[kt][14], st[kt][15]), 0, 0);
        u32x4 w0 = { a0.x, a1.x, a0.y, a1.y };
        u32x4 w1 = { b0.x, b1.x, b0.y, b1.y };
        pfr[kt * 2]     = __builtin_bit_cast(bfrag, w0);
        pfr[kt * 2 + 1] = __builtin_bit_cast(bfrag, w1);
      }
      __builtin_amdgcn_s_setprio(1);
#pragma unroll
      for (int ks = 0; ks < 4; ++ks) {
        const char* vb = (const char*)Vs[cur] + l31 * 128 + ((ks * 32 + hi * 16) ^ sw);
#pragma unroll
        for (int dt = 0; dt < 4; ++dt) {
          bfrag vf = *(const bfrag*)(vb + dt * 4096);
          o[dt] = __builtin_amdgcn_mfma_f32_32x32x16_bf16(vf, pfr[ks], o[dt], 0, 0, 0);
        }
      }
      __builtin_amdgcn_s_setprio(0);
    }
    __syncthreads();
    if (pf) {
#pragma unroll
      for (int i = 0; i < 2; ++i) {
        *(s16x8*)((char*)Ks[cur ^ 1] + kldst[i]) = kr_[i];
        *(s16x8*)((char*)Vs[cur ^ 1] + vldst[i]) = vr_[i];
      }
    }
    __syncthreads();
  }
  const float linv = 1.f / l;
  short* aop = ao + (size_t)(b * 2048 + qg) * 4096 + h * 128 + 4 * hi;
#pragma unroll
  for (int dt = 0; dt < 4; ++dt)
#pragma unroll
    for (int r = 0; r < 16; ++r) {
      int d = dt * 32 + (r & 3) + 8 * (r >> 2);
      aop[d] = f2bf(o[dt][r] * linv);
    }
}

// ---------- launch ----------
extern "C" void kernel_launch(void* const* d_in, const int* in_sizes, int n_in,
                              void* d_out, int out_size, void* d_ws, size_t ws_size,
                              hipStream_t stream) {
  const float* x  = (const float*)d_in[0];
  const float* wq = (const float*)d_in[1];
  const float* wk = (const float*)d_in[2];
  const float* wv = (const float*)d_in[3];
  const float* wo = (const float*)d_in[4];
  const float* fc = (const float*)d_in[7];
  const float* fs = (const float*)d_in[8];

  char* ws = (char*)d_ws;
  short* xb    = (short*)(ws);                    // [4096][4096] bf16; reused as ao
  short* ao    = xb;
  short* wqkvb = (short*)(ws + 33554432ull);      // [6144][4096] bf16; reused as wob
  short* wob   = wqkvb;
  short* qkv   = (short*)(ws + 83886080ull);      // [4096][6144] bf16
  short* vt    = (short*)(ws + 134217728ull);     // [2][8][128][2048] bf16

  cvt4<<<40960, 256, 0, stream>>>(x, wq, wk, wv,
                                  xb, wqkvb, wqkvb + 16777216, wqkvb + 20971520);
  gemm32k<true ><<<768, 512, 0, stream>>>(xb, wqkvb, qkv, 4096, 6144, 4096, 24);
  rope_k<<<4096, 256, 0, stream>>>(qkv, fc, fs);
  vtrans<<<dim3(32, 8, 2), 256, 0, stream>>>(qkv, vt);
  cvt_f32_bf16<<<16384, 256, 0, stream>>>(wo, wob, 4194304);
  fattn2<<<dim3(8, 32, 2), 512, 0, stream>>>(qkv, vt, ao);
  gemm32k<false><<<512, 512, 0, stream>>>(ao, wob, (float*)d_out, 4096, 4096, 4096, 16);
}

// Round 10
// 541.624 us; speedup vs baseline: 1.2804x; 1.2804x over previous
//
#include <hip/hip_runtime.h>
#include <hip/hip_bf16.h>
#include <math.h>

// ---------- types ----------
typedef __attribute__((ext_vector_type(8)))  __bf16 bfrag;   // MFMA A/B operand (8 bf16)
typedef __attribute__((ext_vector_type(4)))  float  f32x4;
typedef __attribute__((ext_vector_type(16))) float  f32x16;  // 32x32 MFMA C/D
typedef __attribute__((ext_vector_type(8)))  short  s16x8;
typedef __attribute__((ext_vector_type(4)))  short  s16x4;
typedef __attribute__((ext_vector_type(2)))  unsigned u32x2;
typedef __attribute__((ext_vector_type(4)))  unsigned u32x4;

__device__ __forceinline__ short f2bf(float f) {
  return (short)__builtin_bit_cast(unsigned short, (__bf16)f);
}
__device__ __forceinline__ float bf2f(short s) {
  return (float)__builtin_bit_cast(__bf16, (unsigned short)s);
}
__device__ __forceinline__ unsigned cvtpk(float lo, float hi_) {
  unsigned r;
  asm("v_cvt_pk_bf16_f32 %0, %1, %2" : "=v"(r) : "v"(lo), "v"(hi_));
  return r;
}
__device__ __forceinline__ void gll16(const void* g, void* l) {
  __builtin_amdgcn_global_load_lds((const __attribute__((address_space(1))) void*)g,
                                   (__attribute__((address_space(3))) void*)l, 16, 0, 0);
}

// ---------- merged f32 -> bf16 convert: x | wq | wk | wv | wo (one launch) ----------
__global__ __launch_bounds__(256) void cvt5(const float* __restrict__ x,
                                            const float* __restrict__ wq,
                                            const float* __restrict__ wk,
                                            const float* __restrict__ wv,
                                            const float* __restrict__ wo,
                                            short* __restrict__ xb,
                                            short* __restrict__ wqb,
                                            short* __restrict__ wkb,
                                            short* __restrict__ wvb,
                                            short* __restrict__ wob) {
  const int b = blockIdx.x;
  const float* in; short* out; int base;
  if (b < 16384)      { in = x;  out = xb;  base = 0; }
  else if (b < 32768) { in = wq; out = wqb; base = 16384 * 256; }
  else if (b < 36864) { in = wk; out = wkb; base = 32768 * 256; }
  else if (b < 40960) { in = wv; out = wvb; base = 36864 * 256; }
  else                { in = wo; out = wob; base = 40960 * 256; }
  const int idx = b * 256 + threadIdx.x - base;
  f32x4 v = ((const f32x4*)in)[idx];
  s16x4 o;
  o.x = f2bf(v.x); o.y = f2bf(v.y); o.z = f2bf(v.z); o.w = f2bf(v.w);
  ((s16x4*)out)[idx] = o;
}

// ---------- GEMM 128x256 tile, BK=64, 2-phase free-run (round-8 best-known) ----------
// C[M][N] = A[M][K] @ B[N][K]^T, bf16 in. 8 waves (2M x 4N), 512 threads.
// Per K-tile: p0 {RD_A(8)+RD_Blo(4); STG Bhi(kt+1)->buf^1; 16 MFMA} midbar
//             p1 {RD_Bhi(4); STG A(kt+2)+Blo(kt+2)->buf; 16 MFMA} vmcnt(4) bar
template<bool BF16OUT>
__global__ __launch_bounds__(512) void gemm128n(const short* __restrict__ A,
                                                const short* __restrict__ B,
                                                void* __restrict__ Cv,
                                                int M, int N, int K, int NBX) {
  __shared__ __align__(16) short As[2][128 * 64];   // 2 x 16 KB
  __shared__ __align__(16) short Bs[2][256 * 64];   // 2 x 32 KB (total 96 KB)
  const int tid = threadIdx.x, lane = tid & 63, wid = tid >> 6;
  const int lr = lane & 15, lg = lane >> 4;
  const int wm = wid >> 2, wn = wid & 3;
  // bijective XCD-aware block swizzle (m204)
  const int nwg = gridDim.x, orig = blockIdx.x;
  const int qq = nwg >> 3, rr = nwg & 7, xc = orig & 7, o8 = orig >> 3;
  const int wg = (xc < rr ? xc * (qq + 1) : rr * (qq + 1) + (xc - rr) * qq) + o8;
  const int bm = (wg / NBX) << 7, bn = (wg % NBX) << 8;
  const int NT = K >> 6;
  const int r0 = tid >> 3;                 // row within 64-row stripe
  const int c0 = tid & 7;
  const int csrc = c0 ^ (r0 & 7);          // inverse-swizzled 16B source chunk

#define STG(OP, OPs, boff, bb, hh, kt_)                                          \
  do {                                                                           \
    _Pragma("unroll")                                                            \
    for (int s = 0; s < 2; ++s)                                                  \
      gll16(OP + (size_t)(boff + (hh) * 128 + s * 64 + r0) * K + (kt_) * 64 + csrc * 8, \
            (char*)OPs[bb] + ((hh) * 128 + s * 64 + wid * 8) * 128);             \
  } while (0)

  int ch[2];
#pragma unroll
  for (int ks = 0; ks < 2; ++ks) ch[ks] = (((ks << 2) | lg) ^ (lr & 7)) << 4;
  const int aoff  = (wm * 64 + lr) * 128;   // A LDS byte base (row stride 128B)
  const int boff2 = (wn * 32 + lr) * 128;   // B LDS byte base

#define RD_A(dst, bb)                                                            \
  do {                                                                           \
    const char* ab = (const char*)As[bb] + aoff;                                 \
    _Pragma("unroll") for (int i = 0; i < 4; ++i)                                \
      _Pragma("unroll") for (int ks = 0; ks < 2; ++ks)                           \
        dst[i][ks] = *(const bfrag*)(ab + i * 2048 + ch[ks]);                    \
  } while (0)
#define RD_B(dst, bb, jh)                                                        \
  do {                                                                           \
    const char* bp = (const char*)Bs[bb] + boff2 + (jh) * 16384;                 \
    _Pragma("unroll") for (int j = 0; j < 2; ++j)                                \
      _Pragma("unroll") for (int ks = 0; ks < 2; ++ks)                           \
        dst[j][ks] = *(const bfrag*)(bp + j * 2048 + ch[ks]);                    \
  } while (0)
// ks OUTERMOST: dependent pairs on each acc separated by 8 independent MFMAs
#define MFMA16(af, bf, jh)                                                       \
  do {                                                                           \
    __builtin_amdgcn_s_setprio(1);                                               \
    _Pragma("unroll") for (int ks = 0; ks < 2; ++ks)                             \
      _Pragma("unroll") for (int i = 0; i < 4; ++i)                              \
        _Pragma("unroll") for (int j = 0; j < 2; ++j)                            \
          acc[i][(jh) * 2 + j] = __builtin_amdgcn_mfma_f32_16x16x32_bf16(        \
              af[i][ks], bf[j][ks], acc[i][(jh) * 2 + j], 0, 0, 0);              \
    __builtin_amdgcn_s_setprio(0);                                               \
  } while (0)

  // ---- prologue: A(0), Blo(0), Bhi(0) -> buf0; A(1), Blo(1) -> buf1 ----
  STG(A, As, bm, 0, 0, 0);
  STG(B, Bs, bn, 0, 0, 0);
  STG(B, Bs, bn, 0, 1, 0);
  if (NT > 1) {
    STG(A, As, bm, 1, 0, 1);
    STG(B, Bs, bn, 1, 0, 1);
    asm volatile("s_waitcnt vmcnt(4)" ::: "memory");
  } else {
    asm volatile("s_waitcnt vmcnt(0)" ::: "memory");
  }
  __builtin_amdgcn_s_barrier();
  __builtin_amdgcn_sched_barrier(0);

  f32x4 acc[4][4] = {};
  bfrag a_[4][2], b_lo[2][2], b_hi[2][2];

  for (int kt = 0; kt < NT; ++kt) {
    const int b = kt & 1;
    // ---- p0: quad (A, B_lo); stage B_hi(kt+1) -> buf^1 ----
    RD_A(a_, b);
    RD_B(b_lo, b, 0);
    if (kt + 1 < NT) STG(B, Bs, bn, b ^ 1, 1, kt + 1);
    MFMA16(a_, b_lo, 0);
    __builtin_amdgcn_s_barrier();          // mid: A(kt)/Blo(kt) reads drained by MFMA
    __builtin_amdgcn_sched_barrier(0);
    // ---- p1: quad (A, B_hi); stage A(kt+2), B_lo(kt+2) -> buf ----
    RD_B(b_hi, b, 1);
    if (kt + 2 < NT) {
      STG(A, As, bm, b, 0, kt + 2);
      STG(B, Bs, bn, b, 0, kt + 2);
    }
    MFMA16(a_, b_hi, 1);
    // ---- boundary: kt+1 fully landed; kt+2 stays in flight ----
    if (kt + 1 < NT) {
      if (kt + 2 < NT) asm volatile("s_waitcnt vmcnt(4)" ::: "memory");
      else             asm volatile("s_waitcnt vmcnt(0)" ::: "memory");
      __builtin_amdgcn_s_barrier();
      __builtin_amdgcn_sched_barrier(0);
    }
  }
#undef STG
#undef RD_A
#undef RD_B
#undef MFMA16
  // ---- epilogue ----
  const int rb = bm + wm * 64 + lg * 4, cb = bn + wn * 32 + lr;
#pragma unroll
  for (int i = 0; i < 4; ++i)
#pragma unroll
    for (int jh = 0; jh < 2; ++jh)
#pragma unroll
      for (int j = 0; j < 2; ++j)
#pragma unroll
        for (int r = 0; r < 4; ++r) {
          size_t idx = (size_t)(rb + i * 16 + r) * N + (cb + jh * 128 + j * 16);
          if (BF16OUT) ((short*)Cv)[idx] = f2bf(acc[i][jh * 2 + j][r]);
          else         ((float*)Cv)[idx] = acc[i][jh * 2 + j][r];
        }
}

// ---------- RoPE in-place (q heads 0..31, k heads 32..39) ----------
__global__ __launch_bounds__(256) void rope_k(short* __restrict__ qkv,
                                              const float* __restrict__ fcos,
                                              const float* __restrict__ fsin) {
  const int t = blockIdx.x;
  const int s = t & 2047;
  unsigned* row = (unsigned*)(qkv + (size_t)t * 6144);
  for (int p = threadIdx.x; p < 2560; p += 256) {
    const int h = p >> 6, i = p & 63;
    const int w = h * 64 + i;
    unsigned u = row[w];
    float a  = bf2f((short)(u & 0xffff));
    float b  = bf2f((short)(u >> 16));
    float c  = fcos[s * 64 + i], sn = fsin[s * 64 + i];
    float na = a * c - b * sn;
    float nb = a * sn + b * c;
    row[w] = ((unsigned)(unsigned short)f2bf(na)) |
             (((unsigned)(unsigned short)f2bf(nb)) << 16);
  }
}

// ---------- V transpose: qkv V-part [t][d] -> vt[b][kvh][d][s] ----------
__global__ __launch_bounds__(256) void vtrans(const short* __restrict__ qkv,
                                              short* __restrict__ vt) {
  const int sb = blockIdx.x, kvh = blockIdx.y, b = blockIdx.z;
  __shared__ short T[64][136];
  const int tid = threadIdx.x;
#pragma unroll
  for (int it = 0; it < 4; ++it) {
    int c = it * 256 + tid;
    int r = c >> 4, dc = c & 15;
    s16x8 v = *(const s16x8*)(qkv + (size_t)(b * 2048 + sb * 64 + r) * 6144
                              + 5120 + kvh * 128 + dc * 8);
    *(s16x8*)&T[r][dc * 8] = v;
  }
  __syncthreads();
#pragma unroll
  for (int it = 0; it < 4; ++it) {
    int c = it * 256 + tid;
    int d = c >> 3, sc = c & 7;
    s16x8 v;
#pragma unroll
    for (int j = 0; j < 8; ++j) v[j] = T[sc * 8 + j][d];
    *(s16x8*)(vt + (size_t)((b * 8 + kvh) * 128 + d) * 2048 + sb * 64 + sc * 8) = v;
  }
}

// ---------- Flash attention, m214 structure; qb<->z balance flip ----------
// Work per block ~ (qb+1). HW pairs block c with c+256 on the same CU and
// (c+256)&7 == c&7, so without the flip both resident blocks share qb ->
// CU load 2(qb+1), makespan 16 units. Flipping qb for z=1 pairs qb=w with
// qb=7-w: every CU gets exactly 9 units.
__global__ __launch_bounds__(512, 2) void fattn2(const short* __restrict__ qkv,
                                                 const short* __restrict__ vt,
                                                 short* __restrict__ ao) {
  const int b = blockIdx.z, h = blockIdx.y;
  const int qb = b ? (int)gridDim.x - 1 - blockIdx.x : blockIdx.x;
  const int kvh = h >> 2;
  const int tid = threadIdx.x;
  const int lane = tid & 63, wid = tid >> 6;
  const int l31 = lane & 31, hi = lane >> 5;
  __shared__ __align__(16) short Ks[2][64 * 128];
  __shared__ __align__(16) short Vs[2][128 * 64];

  const int q0w   = qb * 256 + wid * 32;
  const int qg    = q0w + l31;
  const int tmaxw = q0w >> 6;
  const int NT    = 4 * qb + 4;

  bfrag qf[8];
  {
    const short* qp = qkv + (size_t)(b * 2048 + qg) * 6144 + h * 128 + hi * 8;
#pragma unroll
    for (int kk = 0; kk < 8; ++kk) qf[kk] = *(const bfrag*)(qp + kk * 16);
  }

  const int kr0 = tid >> 4, kcc = tid & 15;
  const int vd0 = tid >> 3, vkc = tid & 7;
  const int kro[2] = { kr0, kr0 + 32 };
  const int vdo[2] = { vd0, vd0 + 64 };
  int kldst[2], vldst[2];
#pragma unroll
  for (int i = 0; i < 2; ++i) {
    kldst[i] = (kro[i] * 256 + kcc * 16) ^ ((kro[i] & 7) << 4);
    vldst[i] = (vdo[i] * 128 + vkc * 16) ^ ((vdo[i] & 7) << 4);
  }
  const short* base_k = qkv + (size_t)(b * 2048) * 6144 + 4096 + kvh * 128;
  const short* base_v = vt + (size_t)((b * 8 + kvh) * 128) * 2048;

  {
    s16x8 kr_[2], vr_[2];
#pragma unroll
    for (int i = 0; i < 2; ++i) {
      kr_[i] = *(const s16x8*)(base_k + (size_t)kro[i] * 6144 + kcc * 8);
      vr_[i] = *(const s16x8*)(base_v + (size_t)vdo[i] * 2048 + vkc * 8);
    }
#pragma unroll
    for (int i = 0; i < 2; ++i) {
      *(s16x8*)((char*)Ks[0] + kldst[i]) = kr_[i];
      *(s16x8*)((char*)Vs[0] + vldst[i]) = vr_[i];
    }
  }
  __syncthreads();

  f32x16 o[4] = {};
  float m = -3.0e38f, l = 0.f;
  const float c0 = 0.08838834764831845f * 1.4426950408889634f;
  const int  sw = (l31 & 7) << 4;

  for (int t = 0; t < NT; ++t) {
    const int cur = t & 1;
    s16x8 kr_[2], vr_[2];
    const bool pf = (t + 1 < NT);
    if (pf) {
#pragma unroll
      for (int i = 0; i < 2; ++i) {
        kr_[i] = *(const s16x8*)(base_k + (size_t)((t + 1) * 64 + kro[i]) * 6144 + kcc * 8);
        vr_[i] = *(const s16x8*)(base_v + (size_t)vdo[i] * 2048 + (t + 1) * 64 + vkc * 8);
      }
    }
    if (t <= tmaxw) {
      // ---- S^T = K @ Q : two chains interleaved (kk outer) ----
      f32x16 st[2] = {};
      {
        const char* kb = (const char*)Ks[cur] + l31 * 256;
        __builtin_amdgcn_s_setprio(1);
#pragma unroll
        for (int kk = 0; kk < 8; ++kk) {
          const int ko = (kk * 32 + hi * 16) ^ sw;
          bfrag kf0 = *(const bfrag*)(kb + ko);
          bfrag kf1 = *(const bfrag*)(kb + 8192 + ko);
          st[0] = __builtin_amdgcn_mfma_f32_32x32x16_bf16(kf0, qf[kk], st[0], 0, 0, 0);
          st[1] = __builtin_amdgcn_mfma_f32_32x32x16_bf16(kf1, qf[kk], st[1], 0, 0, 0);
        }
        __builtin_amdgcn_s_setprio(0);
      }
      if (t == tmaxw) {
        const int kb0 = t * 64 + 4 * hi;
#pragma unroll
        for (int kt = 0; kt < 2; ++kt)
#pragma unroll
          for (int r = 0; r < 16; ++r) {
            int k = kb0 + kt * 32 + (r & 3) + 8 * (r >> 2);
            if (k > qg) st[kt][r] = -3.0e38f;
          }
      }
      float mt = -3.0e38f;
#pragma unroll
      for (int kt = 0; kt < 2; ++kt)
#pragma unroll
        for (int r = 0; r < 16; ++r) mt = fmaxf(mt, st[kt][r]);
      mt = fmaxf(mt, __shfl_xor(mt, 32, 64));
      if (!__all((mt - m) * c0 <= 8.0f)) {
        float nm = fmaxf(m, mt);
        float fe = exp2f((m - nm) * c0);
        m = nm;
        l *= fe;
#pragma unroll
        for (int dt = 0; dt < 4; ++dt)
#pragma unroll
          for (int r = 0; r < 16; ++r) o[dt][r] *= fe;
      }
      const float mc = m * c0;
      float ps = 0.f;
#pragma unroll
      for (int kt = 0; kt < 2; ++kt)
#pragma unroll
        for (int r = 0; r < 16; ++r) {
          float p = exp2f(st[kt][r] * c0 - mc);
          st[kt][r] = p;
          ps += p;
        }
      ps += __shfl_xor(ps, 32, 64);
      l += ps;
      bfrag pfr[4];
#pragma unroll
      for (int kt = 0; kt < 2; ++kt) {
        u32x2 a0 = __builtin_amdgcn_permlane32_swap(cvtpk(st[kt][0],  st[kt][1]),
                                                    cvtpk(st[kt][4],  st[kt][5]),  0, 0);
        u32x2 a1 = __builtin_amdgcn_permlane32_swap(cvtpk(st[kt][2],  st[kt][3]),
                                                    cvtpk(st[kt][6],  st[kt][7]),  0, 0);
        u32x2 b0 = __builtin_amdgcn_permlane32_swap(cvtpk(st[kt][8],  st[kt][9]),
                                                    cvtpk(st[kt][12], st[kt][13]), 0, 0);
        u32x2 b1 = __builtin_amdgcn_permlane32_swap(cvtpk(st[kt][10], st[kt][11]),
                                                    cvtpk(st[kt][14], st[kt][15]), 0, 0);
        u32x4 w0 = { a0.x, a1.x, a0.y, a1.y };
        u32x4 w1 = { b0.x, b1.x, b0.y, b1.y };
        pfr[kt * 2]     = __builtin_bit_cast(bfrag, w0);
        pfr[kt * 2 + 1] = __builtin_bit_cast(bfrag, w1);
      }
      __builtin_amdgcn_s_setprio(1);
#pragma unroll
      for (int ks = 0; ks < 4; ++ks) {
        const char* vb = (const char*)Vs[cur] + l31 * 128 + ((ks * 32 + hi * 16) ^ sw);
#pragma unroll
        for (int dt = 0; dt < 4; ++dt) {
          bfrag vf = *(const bfrag*)(vb + dt * 4096);
          o[dt] = __builtin_amdgcn_mfma_f32_32x32x16_bf16(vf, pfr[ks], o[dt], 0, 0, 0);
        }
      }
      __builtin_amdgcn_s_setprio(0);
    }
    __syncthreads();
    if (pf) {
#pragma unroll
      for (int i = 0; i < 2; ++i) {
        *(s16x8*)((char*)Ks[cur ^ 1] + kldst[i]) = kr_[i];
        *(s16x8*)((char*)Vs[cur ^ 1] + vldst[i]) = vr_[i];
      }
    }
    __syncthreads();
  }
  const float linv = 1.f / l;
  short* aop = ao + (size_t)(b * 2048 + qg) * 4096 + h * 128 + 4 * hi;
#pragma unroll
  for (int dt = 0; dt < 4; ++dt)
#pragma unroll
    for (int r = 0; r < 16; ++r) {
      int d = dt * 32 + (r & 3) + 8 * (r >> 2);
      aop[d] = f2bf(o[dt][r] * linv);
    }
}

// ---------- launch ----------
extern "C" void kernel_launch(void* const* d_in, const int* in_sizes, int n_in,
                              void* d_out, int out_size, void* d_ws, size_t ws_size,
                              hipStream_t stream) {
  const float* x  = (const float*)d_in[0];
  const float* wq = (const float*)d_in[1];
  const float* wk = (const float*)d_in[2];
  const float* wv = (const float*)d_in[3];
  const float* wo = (const float*)d_in[4];
  const float* fc = (const float*)d_in[7];
  const float* fs = (const float*)d_in[8];

  char* ws = (char*)d_ws;
  short* xb    = (short*)(ws);                    // [4096][4096] bf16; reused as ao
  short* ao    = xb;
  short* wqkvb = (short*)(ws + 33554432ull);      // [6144][4096] bf16
  short* qkv   = (short*)(ws + 83886080ull);      // [4096][6144] bf16
  short* vt    = (short*)(ws + 134217728ull);     // [2][8][128][2048] bf16
  short* wob   = (short*)(ws + 167772160ull);     // [4096][4096] bf16

  cvt5<<<57344, 256, 0, stream>>>(x, wq, wk, wv, wo,
                                  xb, wqkvb, wqkvb + 16777216, wqkvb + 20971520, wob);
  gemm128n<true ><<<768, 512, 0, stream>>>(xb, wqkvb, qkv, 4096, 6144, 4096, 24);
  rope_k<<<4096, 256, 0, stream>>>(qkv, fc, fs);
  vtrans<<<dim3(32, 8, 2), 256, 0, stream>>>(qkv, vt);
  fattn2<<<dim3(8, 32, 2), 512, 0, stream>>>(qkv, vt, ao);
  gemm128n<false><<<512, 512, 0, stream>>>(ao, wob, (float*)d_out, 4096, 4096, 4096, 16);
}

// Round 11
// 524.503 us; speedup vs baseline: 1.3222x; 1.0326x over previous
//
#include <hip/hip_runtime.h>
#include <hip/hip_bf16.h>
#include <math.h>

// ---------- types ----------
typedef __attribute__((ext_vector_type(8)))  __bf16 bfrag;   // MFMA A/B operand (8 bf16)
typedef __attribute__((ext_vector_type(4)))  float  f32x4;
typedef __attribute__((ext_vector_type(16))) float  f32x16;  // 32x32 MFMA C/D
typedef __attribute__((ext_vector_type(8)))  short  s16x8;
typedef __attribute__((ext_vector_type(4)))  short  s16x4;
typedef __attribute__((ext_vector_type(2)))  unsigned u32x2;
typedef __attribute__((ext_vector_type(4)))  unsigned u32x4;

__device__ __forceinline__ short f2bf(float f) {
  return (short)__builtin_bit_cast(unsigned short, (__bf16)f);
}
__device__ __forceinline__ float bf2f(short s) {
  return (float)__builtin_bit_cast(__bf16, (unsigned short)s);
}
__device__ __forceinline__ unsigned cvtpk(float lo, float hi_) {
  unsigned r;
  asm("v_cvt_pk_bf16_f32 %0, %1, %2" : "=v"(r) : "v"(lo), "v"(hi_));
  return r;
}
__device__ __forceinline__ void gll16(const void* g, void* l) {
  __builtin_amdgcn_global_load_lds((const __attribute__((address_space(1))) void*)g,
                                   (__attribute__((address_space(3))) void*)l, 16, 0, 0);
}

// ---------- f32 -> bf16 converts ----------
__global__ __launch_bounds__(256) void cvt_f32_bf16(const float* __restrict__ in,
                                                    short* __restrict__ out, int n4) {
  int i = blockIdx.x * 256 + threadIdx.x;
  if (i >= n4) return;
  f32x4 v = ((const f32x4*)in)[i];
  s16x4 o;
  o.x = f2bf(v.x); o.y = f2bf(v.y); o.z = f2bf(v.z); o.w = f2bf(v.w);
  ((s16x4*)out)[i] = o;
}

// merged x|wq|wk|wv convert (one launch, 40960 blocks) — wo converted LATER so
// its streaming traffic doesn't evict the GEMM's L3 working set (r10 lesson).
__global__ __launch_bounds__(256) void cvt4(const float* __restrict__ x,
                                            const float* __restrict__ wq,
                                            const float* __restrict__ wk,
                                            const float* __restrict__ wv,
                                            short* __restrict__ xb,
                                            short* __restrict__ wqb,
                                            short* __restrict__ wkb,
                                            short* __restrict__ wvb) {
  const int b = blockIdx.x;
  const float* in; short* out; int base;
  if (b < 16384)      { in = x;  out = xb;  base = 0; }
  else if (b < 32768) { in = wq; out = wqb; base = 16384 * 256; }
  else if (b < 36864) { in = wk; out = wkb; base = 32768 * 256; }
  else                { in = wv; out = wvb; base = 36864 * 256; }
  const int idx = b * 256 + threadIdx.x - base;
  f32x4 v = ((const f32x4*)in)[idx];
  s16x4 o;
  o.x = f2bf(v.x); o.y = f2bf(v.y); o.z = f2bf(v.z); o.w = f2bf(v.w);
  ((s16x4*)out)[idx] = o;
}

// ---------- GEMM 128x256 tile, BK=64, 2-phase free-run (round-8 best-known) ----------
// C[M][N] = A[M][K] @ B[N][K]^T, bf16 in. 8 waves (2M x 4N), 512 threads.
// Per K-tile: p0 {RD_A(8)+RD_Blo(4); STG Bhi(kt+1)->buf^1; 16 MFMA} midbar
//             p1 {RD_Bhi(4); STG A(kt+2)+Blo(kt+2)->buf; 16 MFMA} vmcnt(4) bar
// NOTE (r10): this kernel is fetch-bound (~615MB @ ~2.9TB/s == its duration);
// keep upstream cache pollution away from it.
template<bool BF16OUT>
__global__ __launch_bounds__(512) void gemm128n(const short* __restrict__ A,
                                                const short* __restrict__ B,
                                                void* __restrict__ Cv,
                                                int M, int N, int K, int NBX) {
  __shared__ __align__(16) short As[2][128 * 64];   // 2 x 16 KB
  __shared__ __align__(16) short Bs[2][256 * 64];   // 2 x 32 KB (total 96 KB)
  const int tid = threadIdx.x, lane = tid & 63, wid = tid >> 6;
  const int lr = lane & 15, lg = lane >> 4;
  const int wm = wid >> 2, wn = wid & 3;
  // bijective XCD-aware block swizzle (m204)
  const int nwg = gridDim.x, orig = blockIdx.x;
  const int qq = nwg >> 3, rr = nwg & 7, xc = orig & 7, o8 = orig >> 3;
  const int wg = (xc < rr ? xc * (qq + 1) : rr * (qq + 1) + (xc - rr) * qq) + o8;
  const int bm = (wg / NBX) << 7, bn = (wg % NBX) << 8;
  const int NT = K >> 6;
  const int r0 = tid >> 3;                 // row within 64-row stripe
  const int c0 = tid & 7;
  const int csrc = c0 ^ (r0 & 7);          // inverse-swizzled 16B source chunk

#define STG(OP, OPs, boff, bb, hh, kt_)                                          \
  do {                                                                           \
    _Pragma("unroll")                                                            \
    for (int s = 0; s < 2; ++s)                                                  \
      gll16(OP + (size_t)(boff + (hh) * 128 + s * 64 + r0) * K + (kt_) * 64 + csrc * 8, \
            (char*)OPs[bb] + ((hh) * 128 + s * 64 + wid * 8) * 128);             \
  } while (0)

  int ch[2];
#pragma unroll
  for (int ks = 0; ks < 2; ++ks) ch[ks] = (((ks << 2) | lg) ^ (lr & 7)) << 4;
  const int aoff  = (wm * 64 + lr) * 128;   // A LDS byte base (row stride 128B)
  const int boff2 = (wn * 32 + lr) * 128;   // B LDS byte base

#define RD_A(dst, bb)                                                            \
  do {                                                                           \
    const char* ab = (const char*)As[bb] + aoff;                                 \
    _Pragma("unroll") for (int i = 0; i < 4; ++i)                                \
      _Pragma("unroll") for (int ks = 0; ks < 2; ++ks)                           \
        dst[i][ks] = *(const bfrag*)(ab + i * 2048 + ch[ks]);                    \
  } while (0)
#define RD_B(dst, bb, jh)                                                        \
  do {                                                                           \
    const char* bp = (const char*)Bs[bb] + boff2 + (jh) * 16384;                 \
    _Pragma("unroll") for (int j = 0; j < 2; ++j)                                \
      _Pragma("unroll") for (int ks = 0; ks < 2; ++ks)                           \
        dst[j][ks] = *(const bfrag*)(bp + j * 2048 + ch[ks]);                    \
  } while (0)
// ks OUTERMOST: dependent pairs on each acc separated by 8 independent MFMAs
#define MFMA16(af, bf, jh)                                                       \
  do {                                                                           \
    __builtin_amdgcn_s_setprio(1);                                               \
    _Pragma("unroll") for (int ks = 0; ks < 2; ++ks)                             \
      _Pragma("unroll") for (int i = 0; i < 4; ++i)                              \
        _Pragma("unroll") for (int j = 0; j < 2; ++j)                            \
          acc[i][(jh) * 2 + j] = __builtin_amdgcn_mfma_f32_16x16x32_bf16(        \
              af[i][ks], bf[j][ks], acc[i][(jh) * 2 + j], 0, 0, 0);              \
    __builtin_amdgcn_s_setprio(0);                                               \
  } while (0)

  // ---- prologue: A(0), Blo(0), Bhi(0) -> buf0; A(1), Blo(1) -> buf1 ----
  STG(A, As, bm, 0, 0, 0);
  STG(B, Bs, bn, 0, 0, 0);
  STG(B, Bs, bn, 0, 1, 0);
  if (NT > 1) {
    STG(A, As, bm, 1, 0, 1);
    STG(B, Bs, bn, 1, 0, 1);
    asm volatile("s_waitcnt vmcnt(4)" ::: "memory");
  } else {
    asm volatile("s_waitcnt vmcnt(0)" ::: "memory");
  }
  __builtin_amdgcn_s_barrier();
  __builtin_amdgcn_sched_barrier(0);

  f32x4 acc[4][4] = {};
  bfrag a_[4][2], b_lo[2][2], b_hi[2][2];

  for (int kt = 0; kt < NT; ++kt) {
    const int b = kt & 1;
    // ---- p0: quad (A, B_lo); stage B_hi(kt+1) -> buf^1 ----
    RD_A(a_, b);
    RD_B(b_lo, b, 0);
    if (kt + 1 < NT) STG(B, Bs, bn, b ^ 1, 1, kt + 1);
    MFMA16(a_, b_lo, 0);
    __builtin_amdgcn_s_barrier();          // mid: A(kt)/Blo(kt) reads drained by MFMA
    __builtin_amdgcn_sched_barrier(0);
    // ---- p1: quad (A, B_hi); stage A(kt+2), B_lo(kt+2) -> buf ----
    RD_B(b_hi, b, 1);
    if (kt + 2 < NT) {
      STG(A, As, bm, b, 0, kt + 2);
      STG(B, Bs, bn, b, 0, kt + 2);
    }
    MFMA16(a_, b_hi, 1);
    // ---- boundary: kt+1 fully landed; kt+2 stays in flight ----
    if (kt + 1 < NT) {
      if (kt + 2 < NT) asm volatile("s_waitcnt vmcnt(4)" ::: "memory");
      else             asm volatile("s_waitcnt vmcnt(0)" ::: "memory");
      __builtin_amdgcn_s_barrier();
      __builtin_amdgcn_sched_barrier(0);
    }
  }
#undef STG
#undef RD_A
#undef RD_B
#undef MFMA16
  // ---- epilogue ----
  const int rb = bm + wm * 64 + lg * 4, cb = bn + wn * 32 + lr;
#pragma unroll
  for (int i = 0; i < 4; ++i)
#pragma unroll
    for (int jh = 0; jh < 2; ++jh)
#pragma unroll
      for (int j = 0; j < 2; ++j)
#pragma unroll
        for (int r = 0; r < 4; ++r) {
          size_t idx = (size_t)(rb + i * 16 + r) * N + (cb + jh * 128 + j * 16);
          if (BF16OUT) ((short*)Cv)[idx] = f2bf(acc[i][jh * 2 + j][r]);
          else         ((float*)Cv)[idx] = acc[i][jh * 2 + j][r];
        }
}

// ---------- RoPE in-place (q heads 0..31, k heads 32..39) ----------
__global__ __launch_bounds__(256) void rope_k(short* __restrict__ qkv,
                                              const float* __restrict__ fcos,
                                              const float* __restrict__ fsin) {
  const int t = blockIdx.x;
  const int s = t & 2047;
  unsigned* row = (unsigned*)(qkv + (size_t)t * 6144);
  for (int p = threadIdx.x; p < 2560; p += 256) {
    const int h = p >> 6, i = p & 63;
    const int w = h * 64 + i;
    unsigned u = row[w];
    float a  = bf2f((short)(u & 0xffff));
    float b  = bf2f((short)(u >> 16));
    float c  = fcos[s * 64 + i], sn = fsin[s * 64 + i];
    float na = a * c - b * sn;
    float nb = a * sn + b * c;
    row[w] = ((unsigned)(unsigned short)f2bf(na)) |
             (((unsigned)(unsigned short)f2bf(nb)) << 16);
  }
}

// ---------- V transpose: qkv V-part [t][d] -> vt[b][kvh][d][s] ----------
__global__ __launch_bounds__(256) void vtrans(const short* __restrict__ qkv,
                                              short* __restrict__ vt) {
  const int sb = blockIdx.x, kvh = blockIdx.y, b = blockIdx.z;
  __shared__ short T[64][136];
  const int tid = threadIdx.x;
#pragma unroll
  for (int it = 0; it < 4; ++it) {
    int c = it * 256 + tid;
    int r = c >> 4, dc = c & 15;
    s16x8 v = *(const s16x8*)(qkv + (size_t)(b * 2048 + sb * 64 + r) * 6144
                              + 5120 + kvh * 128 + dc * 8);
    *(s16x8*)&T[r][dc * 8] = v;
  }
  __syncthreads();
#pragma unroll
  for (int it = 0; it < 4; ++it) {
    int c = it * 256 + tid;
    int d = c >> 3, sc = c & 7;
    s16x8 v;
#pragma unroll
    for (int j = 0; j < 8; ++j) v[j] = T[sc * 8 + j][d];
    *(s16x8*)(vt + (size_t)((b * 8 + kvh) * 128 + d) * 2048 + sb * 64 + sc * 8) = v;
  }
}

// ---------- Flash attention, m214 structure; qb<->z balance flip ----------
__global__ __launch_bounds__(512, 2) void fattn2(const short* __restrict__ qkv,
                                                 const short* __restrict__ vt,
                                                 short* __restrict__ ao) {
  const int b = blockIdx.z, h = blockIdx.y;
  const int qb = b ? (int)gridDim.x - 1 - blockIdx.x : blockIdx.x;
  const int kvh = h >> 2;
  const int tid = threadIdx.x;
  const int lane = tid & 63, wid = tid >> 6;
  const int l31 = lane & 31, hi = lane >> 5;
  __shared__ __align__(16) short Ks[2][64 * 128];
  __shared__ __align__(16) short Vs[2][128 * 64];

  const int q0w   = qb * 256 + wid * 32;
  const int qg    = q0w + l31;
  const int tmaxw = q0w >> 6;
  const int NT    = 4 * qb + 4;

  bfrag qf[8];
  {
    const short* qp = qkv + (size_t)(b * 2048 + qg) * 6144 + h * 128 + hi * 8;
#pragma unroll
    for (int kk = 0; kk < 8; ++kk) qf[kk] = *(const bfrag*)(qp + kk * 16);
  }

  const int kr0 = tid >> 4, kcc = tid & 15;
  const int vd0 = tid >> 3, vkc = tid & 7;
  const int kro[2] = { kr0, kr0 + 32 };
  const int vdo[2] = { vd0, vd0 + 64 };
  int kldst[2], vldst[2];
#pragma unroll
  for (int i = 0; i < 2; ++i) {
    kldst[i] = (kro[i] * 256 + kcc * 16) ^ ((kro[i] & 7) << 4);
    vldst[i] = (vdo[i] * 128 + vkc * 16) ^ ((vdo[i] & 7) << 4);
  }
  const short* base_k = qkv + (size_t)(b * 2048) * 6144 + 4096 + kvh * 128;
  const short* base_v = vt + (size_t)((b * 8 + kvh) * 128) * 2048;

  {
    s16x8 kr_[2], vr_[2];
#pragma unroll
    for (int i = 0; i < 2; ++i) {
      kr_[i] = *(const s16x8*)(base_k + (size_t)kro[i] * 6144 + kcc * 8);
      vr_[i] = *(const s16x8*)(base_v + (size_t)vdo[i] * 2048 + vkc * 8);
    }
#pragma unroll
    for (int i = 0; i < 2; ++i) {
      *(s16x8*)((char*)Ks[0] + kldst[i]) = kr_[i];
      *(s16x8*)((char*)Vs[0] + vldst[i]) = vr_[i];
    }
  }
  __syncthreads();

  f32x16 o[4] = {};
  float m = -3.0e38f, l = 0.f;
  const float c0 = 0.08838834764831845f * 1.4426950408889634f;
  const int  sw = (l31 & 7) << 4;

  for (int t = 0; t < NT; ++t) {
    const int cur = t & 1;
    s16x8 kr_[2], vr_[2];
    const bool pf = (t + 1 < NT);
    if (pf) {
#pragma unroll
      for (int i = 0; i < 2; ++i) {
        kr_[i] = *(const s16x8*)(base_k + (size_t)((t + 1) * 64 + kro[i]) * 6144 + kcc * 8);
        vr_[i] = *(const s16x8*)(base_v + (size_t)vdo[i] * 2048 + (t + 1) * 64 + vkc * 8);
      }
    }
    if (t <= tmaxw) {
      // ---- S^T = K @ Q : two chains interleaved (kk outer) ----
      f32x16 st[2] = {};
      {
        const char* kb = (const char*)Ks[cur] + l31 * 256;
        __builtin_amdgcn_s_setprio(1);
#pragma unroll
        for (int kk = 0; kk < 8; ++kk) {
          const int ko = (kk * 32 + hi * 16) ^ sw;
          bfrag kf0 = *(const bfrag*)(kb + ko);
          bfrag kf1 = *(const bfrag*)(kb + 8192 + ko);
          st[0] = __builtin_amdgcn_mfma_f32_32x32x16_bf16(kf0, qf[kk], st[0], 0, 0, 0);
          st[1] = __builtin_amdgcn_mfma_f32_32x32x16_bf16(kf1, qf[kk], st[1], 0, 0, 0);
        }
        __builtin_amdgcn_s_setprio(0);
      }
      if (t == tmaxw) {
        const int kb0 = t * 64 + 4 * hi;
#pragma unroll
        for (int kt = 0; kt < 2; ++kt)
#pragma unroll
          for (int r = 0; r < 16; ++r) {
            int k = kb0 + kt * 32 + (r & 3) + 8 * (r >> 2);
            if (k > qg) st[kt][r] = -3.0e38f;
          }
      }
      float mt = -3.0e38f;
#pragma unroll
      for (int kt = 0; kt < 2; ++kt)
#pragma unroll
        for (int r = 0; r < 16; ++r) mt = fmaxf(mt, st[kt][r]);
      mt = fmaxf(mt, __shfl_xor(mt, 32, 64));
      if (!__all((mt - m) * c0 <= 8.0f)) {
        float nm = fmaxf(m, mt);
        float fe = exp2f((m - nm) * c0);
        m = nm;
        l *= fe;
#pragma unroll
        for (int dt = 0; dt < 4; ++dt)
#pragma unroll
          for (int r = 0; r < 16; ++r) o[dt][r] *= fe;
      }
      const float mc = m * c0;
      float ps = 0.f;
#pragma unroll
      for (int kt = 0; kt < 2; ++kt)
#pragma unroll
        for (int r = 0; r < 16; ++r) {
          float p = exp2f(st[kt][r] * c0 - mc);
          st[kt][r] = p;
          ps += p;
        }
      ps += __shfl_xor(ps, 32, 64);
      l += ps;
      bfrag pfr[4];
#pragma unroll
      for (int kt = 0; kt < 2; ++kt) {
        u32x2 a0 = __builtin_amdgcn_permlane32_swap(cvtpk(st[kt][0],  st[kt][1]),
                                                    cvtpk(st[kt][4],  st[kt][5]),  0, 0);
        u32x2 a1 = __builtin_amdgcn_permlane32_swap(cvtpk(st[kt][2],  st[kt][3]),
                                                    cvtpk(st[kt][6],  st[kt][7]),  0, 0);
        u32x2 b0 = __builtin_amdgcn_permlane32_swap(cvtpk(st[kt][8],  st[kt][9]),
                                                    cvtpk(st[kt][12], st[kt][13]), 0, 0);
        u32x2 b1 = __builtin_amdgcn_permlane32_swap(cvtpk(st[kt][10], st[kt][11]),
                                                    cvtpk(st[kt][14], st[kt][15]), 0, 0);
        u32x4 w0 = { a0.x, a1.x, a0.y, a1.y };
        u32x4 w1 = { b0.x, b1.x, b0.y, b1.y };
        pfr[kt * 2]     = __builtin_bit_cast(bfrag, w0);
        pfr[kt * 2 + 1] = __builtin_bit_cast(bfrag, w1);
      }
      __builtin_amdgcn_s_setprio(1);
#pragma unroll
      for (int ks = 0; ks < 4; ++ks) {
        const char* vb = (const char*)Vs[cur] + l31 * 128 + ((ks * 32 + hi * 16) ^ sw);
#pragma unroll
        for (int dt = 0; dt < 4; ++dt) {
          bfrag vf = *(const bfrag*)(vb + dt * 4096);
          o[dt] = __builtin_amdgcn_mfma_f32_32x32x16_bf16(vf, pfr[ks], o[dt], 0, 0, 0);
        }
      }
      __builtin_amdgcn_s_setprio(0);
    }
    __syncthreads();
    if (pf) {
#pragma unroll
      for (int i = 0; i < 2; ++i) {
        *(s16x8*)((char*)Ks[cur ^ 1] + kldst[i]) = kr_[i];
        *(s16x8*)((char*)Vs[cur ^ 1] + vldst[i]) = vr_[i];
      }
    }
    __syncthreads();
  }
  const float linv = 1.f / l;
  short* aop = ao + (size_t)(b * 2048 + qg) * 4096 + h * 128 + 4 * hi;
#pragma unroll
  for (int dt = 0; dt < 4; ++dt)
#pragma unroll
    for (int r = 0; r < 16; ++r) {
      int d = dt * 32 + (r & 3) + 8 * (r >> 2);
      aop[d] = f2bf(o[dt][r] * linv);
    }
}

// ---------- launch ----------
extern "C" void kernel_launch(void* const* d_in, const int* in_sizes, int n_in,
                              void* d_out, int out_size, void* d_ws, size_t ws_size,
                              hipStream_t stream) {
  const float* x  = (const float*)d_in[0];
  const float* wq = (const float*)d_in[1];
  const float* wk = (const float*)d_in[2];
  const float* wv = (const float*)d_in[3];
  const float* wo = (const float*)d_in[4];
  const float* fc = (const float*)d_in[7];
  const float* fs = (const float*)d_in[8];

  char* ws = (char*)d_ws;
  short* xb    = (short*)(ws);                    // [4096][4096] bf16; reused as ao
  short* ao    = xb;
  short* wqkvb = (short*)(ws + 33554432ull);      // [6144][4096] bf16
  short* qkv   = (short*)(ws + 83886080ull);      // [4096][6144] bf16
  short* vt    = (short*)(ws + 134217728ull);     // [2][8][128][2048] bf16
  short* wob   = (short*)(ws + 167772160ull);     // [4096][4096] bf16

  cvt4<<<40960, 256, 0, stream>>>(x, wq, wk, wv,
                                  xb, wqkvb, wqkvb + 16777216, wqkvb + 20971520);
  gemm128n<true ><<<768, 512, 0, stream>>>(xb, wqkvb, qkv, 4096, 6144, 4096, 24);
  rope_k<<<4096, 256, 0, stream>>>(qkv, fc, fs);
  vtrans<<<dim3(32, 8, 2), 256, 0, stream>>>(qkv, vt);
  cvt_f32_bf16<<<16384, 256, 0, stream>>>(wo, wob, 4194304);
  fattn2<<<dim3(8, 32, 2), 512, 0, stream>>>(qkv, vt, ao);
  gemm128n<false><<<512, 512, 0, stream>>>(ao, wob, (float*)d_out, 4096, 4096, 4096, 16);
}

// Round 12
// 504.473 us; speedup vs baseline: 1.3747x; 1.0397x over previous
//
#include <hip/hip_runtime.h>
#include <hip/hip_bf16.h>
#include <math.h>

// ---------- types ----------
typedef __attribute__((ext_vector_type(8)))  __bf16 bfrag;   // MFMA A/B operand (8 bf16)
typedef __attribute__((ext_vector_type(4)))  float  f32x4;
typedef __attribute__((ext_vector_type(16))) float  f32x16;  // 32x32 MFMA C/D
typedef __attribute__((ext_vector_type(8)))  short  s16x8;
typedef __attribute__((ext_vector_type(4)))  short  s16x4;
typedef __attribute__((ext_vector_type(2)))  unsigned u32x2;
typedef __attribute__((ext_vector_type(4)))  unsigned u32x4;

__device__ __forceinline__ short f2bf(float f) {
  return (short)__builtin_bit_cast(unsigned short, (__bf16)f);
}
__device__ __forceinline__ float bf2f(short s) {
  return (float)__builtin_bit_cast(__bf16, (unsigned short)s);
}
__device__ __forceinline__ unsigned cvtpk(float lo, float hi_) {
  unsigned r;
  asm("v_cvt_pk_bf16_f32 %0, %1, %2" : "=v"(r) : "v"(lo), "v"(hi_));
  return r;
}
__device__ __forceinline__ void gll16(const void* g, void* l) {
  __builtin_amdgcn_global_load_lds((const __attribute__((address_space(1))) void*)g,
                                   (__attribute__((address_space(3))) void*)l, 16, 0, 0);
}

// ---------- f32 -> bf16 converts ----------
__global__ __launch_bounds__(256) void cvt_f32_bf16(const float* __restrict__ in,
                                                    short* __restrict__ out, int n4) {
  int i = blockIdx.x * 256 + threadIdx.x;
  if (i >= n4) return;
  f32x4 v = ((const f32x4*)in)[i];
  s16x4 o;
  o.x = f2bf(v.x); o.y = f2bf(v.y); o.z = f2bf(v.z); o.w = f2bf(v.w);
  ((s16x4*)out)[i] = o;
}

// merged x|wq|wk|wv convert (one launch, 40960 blocks) — wo converted LATER so
// its streaming traffic doesn't evict the GEMM's L3 working set (r10 lesson).
__global__ __launch_bounds__(256) void cvt4(const float* __restrict__ x,
                                            const float* __restrict__ wq,
                                            const float* __restrict__ wk,
                                            const float* __restrict__ wv,
                                            short* __restrict__ xb,
                                            short* __restrict__ wqb,
                                            short* __restrict__ wkb,
                                            short* __restrict__ wvb) {
  const int b = blockIdx.x;
  const float* in; short* out; int base;
  if (b < 16384)      { in = x;  out = xb;  base = 0; }
  else if (b < 32768) { in = wq; out = wqb; base = 16384 * 256; }
  else if (b < 36864) { in = wk; out = wkb; base = 32768 * 256; }
  else                { in = wv; out = wvb; base = 36864 * 256; }
  const int idx = b * 256 + threadIdx.x - base;
  f32x4 v = ((const f32x4*)in)[idx];
  s16x4 o;
  o.x = f2bf(v.x); o.y = f2bf(v.y); o.z = f2bf(v.z); o.w = f2bf(v.w);
  ((s16x4*)out)[idx] = o;
}

// ---------- GEMM 128x256 tile, BK=64, 2-phase free-run + L2-compact block map ----------
// C[M][N] = A[M][K] @ B[N][K]^T, bf16 in. 8 waves (2M x 4N), 512 threads.
// Per K-tile: p0 {RD_A(8)+RD_Blo(4); STG Bhi(kt+1)->buf^1; 16 MFMA} midbar
//             p1 {RD_Bhi(4); STG A(kt+2)+Blo(kt+2)->buf; 16 MFMA} vmcnt(4) bar
// Fetch-bound (r10/r11: FETCH tracks dur 1:1 at ~3.1 TB/s). Block map: XCD
// xc = orig&7 owns an 8 x (NBX/2) tile region; within it each dispatch round
// of 32 blocks forms an 8bm x 4bn sub-block -> per-round L2-miss set =
// 8 A-panels + 4 B-panels = 16 MB (vs ~50 MB row-major) -> ~3x less FETCH.
// Requires: gridDim.x == 32*NBX, M==4096, NBX even, NBX/2 multiple of 4.
template<bool BF16OUT>
__global__ __launch_bounds__(512) void gemm128n(const short* __restrict__ A,
                                                const short* __restrict__ B,
                                                void* __restrict__ Cv,
                                                int M, int N, int K, int NBX) {
  __shared__ __align__(16) short As[2][128 * 64];   // 2 x 16 KB
  __shared__ __align__(16) short Bs[2][256 * 64];   // 2 x 32 KB (total 96 KB)
  const int tid = threadIdx.x, lane = tid & 63, wid = tid >> 6;
  const int lr = lane & 15, lg = lane >> 4;
  const int wm = wid >> 2, wn = wid & 3;
  // L2-compact bijective map: orig -> (xc, o8) -> (bmi, bni)
  const int orig = blockIdx.x;
  const int xc = orig & 7, o8 = orig >> 3;
  const int s8 = o8 >> 5, t8 = o8 & 31;            // sub-block index / pos
  const int bmi = ((xc >> 1) << 3) + (t8 >> 2);    // region row*8 + 0..7
  const int bni = (xc & 1) * (NBX >> 1) + (s8 << 2) + (t8 & 3);
  const int bm = bmi << 7, bn = bni << 8;
  const int NT = K >> 6;
  const int r0 = tid >> 3;                 // row within 64-row stripe
  const int c0 = tid & 7;
  const int csrc = c0 ^ (r0 & 7);          // inverse-swizzled 16B source chunk

#define STG(OP, OPs, boff, bb, hh, kt_)                                          \
  do {                                                                           \
    _Pragma("unroll")                                                            \
    for (int s = 0; s < 2; ++s)                                                  \
      gll16(OP + (size_t)(boff + (hh) * 128 + s * 64 + r0) * K + (kt_) * 64 + csrc * 8, \
            (char*)OPs[bb] + ((hh) * 128 + s * 64 + wid * 8) * 128);             \
  } while (0)

  int ch[2];
#pragma unroll
  for (int ks = 0; ks < 2; ++ks) ch[ks] = (((ks << 2) | lg) ^ (lr & 7)) << 4;
  const int aoff  = (wm * 64 + lr) * 128;   // A LDS byte base (row stride 128B)
  const int boff2 = (wn * 32 + lr) * 128;   // B LDS byte base

#define RD_A(dst, bb)                                                            \
  do {                                                                           \
    const char* ab = (const char*)As[bb] + aoff;                                 \
    _Pragma("unroll") for (int i = 0; i < 4; ++i)                                \
      _Pragma("unroll") for (int ks = 0; ks < 2; ++ks)                           \
        dst[i][ks] = *(const bfrag*)(ab + i * 2048 + ch[ks]);                    \
  } while (0)
#define RD_B(dst, bb, jh)                                                        \
  do {                                                                           \
    const char* bp = (const char*)Bs[bb] + boff2 + (jh) * 16384;                 \
    _Pragma("unroll") for (int j = 0; j < 2; ++j)                                \
      _Pragma("unroll") for (int ks = 0; ks < 2; ++ks)                           \
        dst[j][ks] = *(const bfrag*)(bp + j * 2048 + ch[ks]);                    \
  } while (0)
// ks OUTERMOST: dependent pairs on each acc separated by 8 independent MFMAs
#define MFMA16(af, bf, jh)                                                       \
  do {                                                                           \
    __builtin_amdgcn_s_setprio(1);                                               \
    _Pragma("unroll") for (int ks = 0; ks < 2; ++ks)                             \
      _Pragma("unroll") for (int i = 0; i < 4; ++i)                              \
        _Pragma("unroll") for (int j = 0; j < 2; ++j)                            \
          acc[i][(jh) * 2 + j] = __builtin_amdgcn_mfma_f32_16x16x32_bf16(        \
              af[i][ks], bf[j][ks], acc[i][(jh) * 2 + j], 0, 0, 0);              \
    __builtin_amdgcn_s_setprio(0);                                               \
  } while (0)

  // ---- prologue: A(0), Blo(0), Bhi(0) -> buf0; A(1), Blo(1) -> buf1 ----
  STG(A, As, bm, 0, 0, 0);
  STG(B, Bs, bn, 0, 0, 0);
  STG(B, Bs, bn, 0, 1, 0);
  if (NT > 1) {
    STG(A, As, bm, 1, 0, 1);
    STG(B, Bs, bn, 1, 0, 1);
    asm volatile("s_waitcnt vmcnt(4)" ::: "memory");
  } else {
    asm volatile("s_waitcnt vmcnt(0)" ::: "memory");
  }
  __builtin_amdgcn_s_barrier();
  __builtin_amdgcn_sched_barrier(0);

  f32x4 acc[4][4] = {};
  bfrag a_[4][2], b_lo[2][2], b_hi[2][2];

  for (int kt = 0; kt < NT; ++kt) {
    const int b = kt & 1;
    // ---- p0: quad (A, B_lo); stage B_hi(kt+1) -> buf^1 ----
    RD_A(a_, b);
    RD_B(b_lo, b, 0);
    if (kt + 1 < NT) STG(B, Bs, bn, b ^ 1, 1, kt + 1);
    MFMA16(a_, b_lo, 0);
    __builtin_amdgcn_s_barrier();          // mid: A(kt)/Blo(kt) reads drained by MFMA
    __builtin_amdgcn_sched_barrier(0);
    // ---- p1: quad (A, B_hi); stage A(kt+2), B_lo(kt+2) -> buf ----
    RD_B(b_hi, b, 1);
    if (kt + 2 < NT) {
      STG(A, As, bm, b, 0, kt + 2);
      STG(B, Bs, bn, b, 0, kt + 2);
    }
    MFMA16(a_, b_hi, 1);
    // ---- boundary: kt+1 fully landed; kt+2 stays in flight ----
    if (kt + 1 < NT) {
      if (kt + 2 < NT) asm volatile("s_waitcnt vmcnt(4)" ::: "memory");
      else             asm volatile("s_waitcnt vmcnt(0)" ::: "memory");
      __builtin_amdgcn_s_barrier();
      __builtin_amdgcn_sched_barrier(0);
    }
  }
#undef STG
#undef RD_A
#undef RD_B
#undef MFMA16
  // ---- epilogue ----
  const int rb = bm + wm * 64 + lg * 4, cb = bn + wn * 32 + lr;
#pragma unroll
  for (int i = 0; i < 4; ++i)
#pragma unroll
    for (int jh = 0; jh < 2; ++jh)
#pragma unroll
      for (int j = 0; j < 2; ++j)
#pragma unroll
        for (int r = 0; r < 4; ++r) {
          size_t idx = (size_t)(rb + i * 16 + r) * N + (cb + jh * 128 + j * 16);
          if (BF16OUT) ((short*)Cv)[idx] = f2bf(acc[i][jh * 2 + j][r]);
          else         ((float*)Cv)[idx] = acc[i][jh * 2 + j][r];
        }
}

// ---------- RoPE in-place (q heads 0..31, k heads 32..39) ----------
__global__ __launch_bounds__(256) void rope_k(short* __restrict__ qkv,
                                              const float* __restrict__ fcos,
                                              const float* __restrict__ fsin) {
  const int t = blockIdx.x;
  const int s = t & 2047;
  unsigned* row = (unsigned*)(qkv + (size_t)t * 6144);
  for (int p = threadIdx.x; p < 2560; p += 256) {
    const int h = p >> 6, i = p & 63;
    const int w = h * 64 + i;
    unsigned u = row[w];
    float a  = bf2f((short)(u & 0xffff));
    float b  = bf2f((short)(u >> 16));
    float c  = fcos[s * 64 + i], sn = fsin[s * 64 + i];
    float na = a * c - b * sn;
    float nb = a * sn + b * c;
    row[w] = ((unsigned)(unsigned short)f2bf(na)) |
             (((unsigned)(unsigned short)f2bf(nb)) << 16);
  }
}

// ---------- V transpose: qkv V-part [t][d] -> vt[b][kvh][d][s] ----------
__global__ __launch_bounds__(256) void vtrans(const short* __restrict__ qkv,
                                              short* __restrict__ vt) {
  const int sb = blockIdx.x, kvh = blockIdx.y, b = blockIdx.z;
  __shared__ short T[64][136];
  const int tid = threadIdx.x;
#pragma unroll
  for (int it = 0; it < 4; ++it) {
    int c = it * 256 + tid;
    int r = c >> 4, dc = c & 15;
    s16x8 v = *(const s16x8*)(qkv + (size_t)(b * 2048 + sb * 64 + r) * 6144
                              + 5120 + kvh * 128 + dc * 8);
    *(s16x8*)&T[r][dc * 8] = v;
  }
  __syncthreads();
#pragma unroll
  for (int it = 0; it < 4; ++it) {
    int c = it * 256 + tid;
    int d = c >> 3, sc = c & 7;
    s16x8 v;
#pragma unroll
    for (int j = 0; j < 8; ++j) v[j] = T[sc * 8 + j][d];
    *(s16x8*)(vt + (size_t)((b * 8 + kvh) * 128 + d) * 2048 + sb * 64 + sc * 8) = v;
  }
}

// ---------- Flash attention, m214 structure; qb<->z balance flip ----------
__global__ __launch_bounds__(512, 2) void fattn2(const short* __restrict__ qkv,
                                                 const short* __restrict__ vt,
                                                 short* __restrict__ ao) {
  const int b = blockIdx.z, h = blockIdx.y;
  const int qb = b ? (int)gridDim.x - 1 - blockIdx.x : blockIdx.x;
  const int kvh = h >> 2;
  const int tid = threadIdx.x;
  const int lane = tid & 63, wid = tid >> 6;
  const int l31 = lane & 31, hi = lane >> 5;
  __shared__ __align__(16) short Ks[2][64 * 128];
  __shared__ __align__(16) short Vs[2][128 * 64];

  const int q0w   = qb * 256 + wid * 32;
  const int qg    = q0w + l31;
  const int tmaxw = q0w >> 6;
  const int NT    = 4 * qb + 4;

  bfrag qf[8];
  {
    const short* qp = qkv + (size_t)(b * 2048 + qg) * 6144 + h * 128 + hi * 8;
#pragma unroll
    for (int kk = 0; kk < 8; ++kk) qf[kk] = *(const bfrag*)(qp + kk * 16);
  }

  const int kr0 = tid >> 4, kcc = tid & 15;
  const int vd0 = tid >> 3, vkc = tid & 7;
  const int kro[2] = { kr0, kr0 + 32 };
  const int vdo[2] = { vd0, vd0 + 64 };
  int kldst[2], vldst[2];
#pragma unroll
  for (int i = 0; i < 2; ++i) {
    kldst[i] = (kro[i] * 256 + kcc * 16) ^ ((kro[i] & 7) << 4);
    vldst[i] = (vdo[i] * 128 + vkc * 16) ^ ((vdo[i] & 7) << 4);
  }
  const short* base_k = qkv + (size_t)(b * 2048) * 6144 + 4096 + kvh * 128;
  const short* base_v = vt + (size_t)((b * 8 + kvh) * 128) * 2048;

  {
    s16x8 kr_[2], vr_[2];
#pragma unroll
    for (int i = 0; i < 2; ++i) {
      kr_[i] = *(const s16x8*)(base_k + (size_t)kro[i] * 6144 + kcc * 8);
      vr_[i] = *(const s16x8*)(base_v + (size_t)vdo[i] * 2048 + vkc * 8);
    }
#pragma unroll
    for (int i = 0; i < 2; ++i) {
      *(s16x8*)((char*)Ks[0] + kldst[i]) = kr_[i];
      *(s16x8*)((char*)Vs[0] + vldst[i]) = vr_[i];
    }
  }
  __syncthreads();

  f32x16 o[4] = {};
  float m = -3.0e38f, l = 0.f;
  const float c0 = 0.08838834764831845f * 1.4426950408889634f;
  const int  sw = (l31 & 7) << 4;

  for (int t = 0; t < NT; ++t) {
    const int cur = t & 1;
    s16x8 kr_[2], vr_[2];
    const bool pf = (t + 1 < NT);
    if (pf) {
#pragma unroll
      for (int i = 0; i < 2; ++i) {
        kr_[i] = *(const s16x8*)(base_k + (size_t)((t + 1) * 64 + kro[i]) * 6144 + kcc * 8);
        vr_[i] = *(const s16x8*)(base_v + (size_t)vdo[i] * 2048 + (t + 1) * 64 + vkc * 8);
      }
    }
    if (t <= tmaxw) {
      // ---- S^T = K @ Q : two chains interleaved (kk outer) ----
      f32x16 st[2] = {};
      {
        const char* kb = (const char*)Ks[cur] + l31 * 256;
        __builtin_amdgcn_s_setprio(1);
#pragma unroll
        for (int kk = 0; kk < 8; ++kk) {
          const int ko = (kk * 32 + hi * 16) ^ sw;
          bfrag kf0 = *(const bfrag*)(kb + ko);
          bfrag kf1 = *(const bfrag*)(kb + 8192 + ko);
          st[0] = __builtin_amdgcn_mfma_f32_32x32x16_bf16(kf0, qf[kk], st[0], 0, 0, 0);
          st[1] = __builtin_amdgcn_mfma_f32_32x32x16_bf16(kf1, qf[kk], st[1], 0, 0, 0);
        }
        __builtin_amdgcn_s_setprio(0);
      }
      if (t == tmaxw) {
        const int kb0 = t * 64 + 4 * hi;
#pragma unroll
        for (int kt = 0; kt < 2; ++kt)
#pragma unroll
          for (int r = 0; r < 16; ++r) {
            int k = kb0 + kt * 32 + (r & 3) + 8 * (r >> 2);
            if (k > qg) st[kt][r] = -3.0e38f;
          }
      }
      float mt = -3.0e38f;
#pragma unroll
      for (int kt = 0; kt < 2; ++kt)
#pragma unroll
        for (int r = 0; r < 16; ++r) mt = fmaxf(mt, st[kt][r]);
      mt = fmaxf(mt, __shfl_xor(mt, 32, 64));
      if (!__all((mt - m) * c0 <= 8.0f)) {
        float nm = fmaxf(m, mt);
        float fe = exp2f((m - nm) * c0);
        m = nm;
        l *= fe;
#pragma unroll
        for (int dt = 0; dt < 4; ++dt)
#pragma unroll
          for (int r = 0; r < 16; ++r) o[dt][r] *= fe;
      }
      const float mc = m * c0;
      float ps = 0.f;
#pragma unroll
      for (int kt = 0; kt < 2; ++kt)
#pragma unroll
        for (int r = 0; r < 16; ++r) {
          float p = exp2f(st[kt][r] * c0 - mc);
          st[kt][r] = p;
          ps += p;
        }
      ps += __shfl_xor(ps, 32, 64);
      l += ps;
      bfrag pfr[4];
#pragma unroll
      for (int kt = 0; kt < 2; ++kt) {
        u32x2 a0 = __builtin_amdgcn_permlane32_swap(cvtpk(st[kt][0],  st[kt][1]),
                                                    cvtpk(st[kt][4],  st[kt][5]),  0, 0);
        u32x2 a1 = __builtin_amdgcn_permlane32_swap(cvtpk(st[kt][2],  st[kt][3]),
                                                    cvtpk(st[kt][6],  st[kt][7]),  0, 0);
        u32x2 b0 = __builtin_amdgcn_permlane32_swap(cvtpk(st[kt][8],  st[kt][9]),
                                                    cvtpk(st[kt][12], st[kt][13]), 0, 0);
        u32x2 b1 = __builtin_amdgcn_permlane32_swap(cvtpk(st[kt][10], st[kt][11]),
                                                    cvtpk(st[kt][14], st[kt][15]), 0, 0);
        u32x4 w0 = { a0.x, a1.x, a0.y, a1.y };
        u32x4 w1 = { b0.x, b1.x, b0.y, b1.y };
        pfr[kt * 2]     = __builtin_bit_cast(bfrag, w0);
        pfr[kt * 2 + 1] = __builtin_bit_cast(bfrag, w1);
      }
      __builtin_amdgcn_s_setprio(1);
#pragma unroll
      for (int ks = 0; ks < 4; ++ks) {
        const char* vb = (const char*)Vs[cur] + l31 * 128 + ((ks * 32 + hi * 16) ^ sw);
#pragma unroll
        for (int dt = 0; dt < 4; ++dt) {
          bfrag vf = *(const bfrag*)(vb + dt * 4096);
          o[dt] = __builtin_amdgcn_mfma_f32_32x32x16_bf16(vf, pfr[ks], o[dt], 0, 0, 0);
        }
      }
      __builtin_amdgcn_s_setprio(0);
    }
    __syncthreads();
    if (pf) {
#pragma unroll
      for (int i = 0; i < 2; ++i) {
        *(s16x8*)((char*)Ks[cur ^ 1] + kldst[i]) = kr_[i];
        *(s16x8*)((char*)Vs[cur ^ 1] + vldst[i]) = vr_[i];
      }
    }
    __syncthreads();
  }
  const float linv = 1.f / l;
  short* aop = ao + (size_t)(b * 2048 + qg) * 4096 + h * 128 + 4 * hi;
#pragma unroll
  for (int dt = 0; dt < 4; ++dt)
#pragma unroll
    for (int r = 0; r < 16; ++r) {
      int d = dt * 32 + (r & 3) + 8 * (r >> 2);
      aop[d] = f2bf(o[dt][r] * linv);
    }
}

// ---------- launch ----------
extern "C" void kernel_launch(void* const* d_in, const int* in_sizes, int n_in,
                              void* d_out, int out_size, void* d_ws, size_t ws_size,
                              hipStream_t stream) {
  const float* x  = (const float*)d_in[0];
  const float* wq = (const float*)d_in[1];
  const float* wk = (const float*)d_in[2];
  const float* wv = (const float*)d_in[3];
  const float* wo = (const float*)d_in[4];
  const float* fc = (const float*)d_in[7];
  const float* fs = (const float*)d_in[8];

  char* ws = (char*)d_ws;
  short* xb    = (short*)(ws);                    // [4096][4096] bf16; reused as ao
  short* ao    = xb;
  short* wqkvb = (short*)(ws + 33554432ull);      // [6144][4096] bf16
  short* qkv   = (short*)(ws + 83886080ull);      // [4096][6144] bf16
  short* vt    = (short*)(ws + 134217728ull);     // [2][8][128][2048] bf16
  short* wob   = (short*)(ws + 167772160ull);     // [4096][4096] bf16

  cvt4<<<40960, 256, 0, stream>>>(x, wq, wk, wv,
                                  xb, wqkvb, wqkvb + 16777216, wqkvb + 20971520);
  gemm128n<true ><<<768, 512, 0, stream>>>(xb, wqkvb, qkv, 4096, 6144, 4096, 24);
  rope_k<<<4096, 256, 0, stream>>>(qkv, fc, fs);
  vtrans<<<dim3(32, 8, 2), 256, 0, stream>>>(qkv, vt);
  cvt_f32_bf16<<<16384, 256, 0, stream>>>(wo, wob, 4194304);
  fattn2<<<dim3(8, 32, 2), 512, 0, stream>>>(qkv, vt, ao);
  gemm128n<false><<<512, 512, 0, stream>>>(ao, wob, (float*)d_out, 4096, 4096, 4096, 16);
}

// Round 13
// 491.912 us; speedup vs baseline: 1.4098x; 1.0255x over previous
//
#include <hip/hip_runtime.h>
#include <hip/hip_bf16.h>
#include <math.h>

// ---------- types ----------
typedef __attribute__((ext_vector_type(8)))  __bf16 bfrag;   // MFMA A/B operand (8 bf16)
typedef __attribute__((ext_vector_type(4)))  float  f32x4;
typedef __attribute__((ext_vector_type(16))) float  f32x16;  // 32x32 MFMA C/D
typedef __attribute__((ext_vector_type(8)))  short  s16x8;
typedef __attribute__((ext_vector_type(4)))  short  s16x4;
typedef __attribute__((ext_vector_type(2)))  unsigned u32x2;
typedef __attribute__((ext_vector_type(4)))  unsigned u32x4;

__device__ __forceinline__ short f2bf(float f) {
  return (short)__builtin_bit_cast(unsigned short, (__bf16)f);
}
__device__ __forceinline__ float bf2f(short s) {
  return (float)__builtin_bit_cast(__bf16, (unsigned short)s);
}
__device__ __forceinline__ unsigned cvtpk(float lo, float hi_) {
  unsigned r;
  asm("v_cvt_pk_bf16_f32 %0, %1, %2" : "=v"(r) : "v"(lo), "v"(hi_));
  return r;
}
__device__ __forceinline__ void gll16(const void* g, void* l) {
  __builtin_amdgcn_global_load_lds((const __attribute__((address_space(1))) void*)g,
                                   (__attribute__((address_space(3))) void*)l, 16, 0, 0);
}

// ---------- f32 -> bf16 converts ----------
__global__ __launch_bounds__(256) void cvt_f32_bf16(const float* __restrict__ in,
                                                    short* __restrict__ out, int n4) {
  int i = blockIdx.x * 256 + threadIdx.x;
  if (i >= n4) return;
  f32x4 v = ((const f32x4*)in)[i];
  s16x4 o;
  o.x = f2bf(v.x); o.y = f2bf(v.y); o.z = f2bf(v.z); o.w = f2bf(v.w);
  ((s16x4*)out)[i] = o;
}

__global__ __launch_bounds__(256) void cvt4(const float* __restrict__ x,
                                            const float* __restrict__ wq,
                                            const float* __restrict__ wk,
                                            const float* __restrict__ wv,
                                            short* __restrict__ xb,
                                            short* __restrict__ wqb,
                                            short* __restrict__ wkb,
                                            short* __restrict__ wvb) {
  const int b = blockIdx.x;
  const float* in; short* out; int base;
  if (b < 16384)      { in = x;  out = xb;  base = 0; }
  else if (b < 32768) { in = wq; out = wqb; base = 16384 * 256; }
  else if (b < 36864) { in = wk; out = wkb; base = 32768 * 256; }
  else                { in = wv; out = wvb; base = 36864 * 256; }
  const int idx = b * 256 + threadIdx.x - base;
  f32x4 v = ((const f32x4*)in)[idx];
  s16x4 o;
  o.x = f2bf(v.x); o.y = f2bf(v.y); o.z = f2bf(v.z); o.w = f2bf(v.w);
  ((s16x4*)out)[idx] = o;
}

// ---------- shared staging macro (half-tile = 128 rows x 64 cols, 2 gll16/thr) ----------
#define STG_(OP, OPs, boff, bb, hh, kt_, Kd)                                     \
  do {                                                                           \
    _Pragma("unroll")                                                            \
    for (int s = 0; s < 2; ++s)                                                  \
      gll16(OP + (size_t)(boff + (hh) * 128 + s * 64 + r0) * Kd + (kt_) * 64 + csrc * 8, \
            (char*)OPs[bb] + ((hh) * 128 + s * 64 + wid * 8) * 128);             \
  } while (0)

// ---------- GEMM 128x256 tile (round-12, for QKV; 768 blocks) ----------
template<bool BF16OUT>
__global__ __launch_bounds__(512) void gemm128n(const short* __restrict__ A,
                                                const short* __restrict__ B,
                                                void* __restrict__ Cv,
                                                int M, int N, int K, int NBX) {
  __shared__ __align__(16) short As[2][128 * 64];
  __shared__ __align__(16) short Bs[2][256 * 64];
  const int tid = threadIdx.x, lane = tid & 63, wid = tid >> 6;
  const int lr = lane & 15, lg = lane >> 4;
  const int wm = wid >> 2, wn = wid & 3;
  const int orig = blockIdx.x;
  const int xc = orig & 7, o8 = orig >> 3;
  const int s8 = o8 >> 5, t8 = o8 & 31;
  const int bmi = ((xc >> 1) << 3) + (t8 >> 2);
  const int bni = (xc & 1) * (NBX >> 1) + (s8 << 2) + (t8 & 3);
  const int bm = bmi << 7, bn = bni << 8;
  const int NT = K >> 6;
  const int r0 = tid >> 3;
  const int c0 = tid & 7;
  const int csrc = c0 ^ (r0 & 7);

  int ch[2];
#pragma unroll
  for (int ks = 0; ks < 2; ++ks) ch[ks] = (((ks << 2) | lg) ^ (lr & 7)) << 4;
  const int aoff  = (wm * 64 + lr) * 128;
  const int boff2 = (wn * 32 + lr) * 128;

#define RD_A(dst, bb)                                                            \
  do {                                                                           \
    const char* ab = (const char*)As[bb] + aoff;                                 \
    _Pragma("unroll") for (int i = 0; i < 4; ++i)                                \
      _Pragma("unroll") for (int ks = 0; ks < 2; ++ks)                           \
        dst[i][ks] = *(const bfrag*)(ab + i * 2048 + ch[ks]);                    \
  } while (0)
#define RD_B(dst, bb, jh)                                                        \
  do {                                                                           \
    const char* bp = (const char*)Bs[bb] + boff2 + (jh) * 16384;                 \
    _Pragma("unroll") for (int j = 0; j < 2; ++j)                                \
      _Pragma("unroll") for (int ks = 0; ks < 2; ++ks)                           \
        dst[j][ks] = *(const bfrag*)(bp + j * 2048 + ch[ks]);                    \
  } while (0)
#define MFMA16(af, bf, jh)                                                       \
  do {                                                                           \
    __builtin_amdgcn_s_setprio(1);                                               \
    _Pragma("unroll") for (int ks = 0; ks < 2; ++ks)                             \
      _Pragma("unroll") for (int i = 0; i < 4; ++i)                              \
        _Pragma("unroll") for (int j = 0; j < 2; ++j)                            \
          acc[i][(jh) * 2 + j] = __builtin_amdgcn_mfma_f32_16x16x32_bf16(        \
              af[i][ks], bf[j][ks], acc[i][(jh) * 2 + j], 0, 0, 0);              \
    __builtin_amdgcn_s_setprio(0);                                               \
  } while (0)

  STG_(A, As, bm, 0, 0, 0, K);
  STG_(B, Bs, bn, 0, 0, 0, K);
  STG_(B, Bs, bn, 0, 1, 0, K);
  if (NT > 1) {
    STG_(A, As, bm, 1, 0, 1, K);
    STG_(B, Bs, bn, 1, 0, 1, K);
    asm volatile("s_waitcnt vmcnt(4)" ::: "memory");
  } else {
    asm volatile("s_waitcnt vmcnt(0)" ::: "memory");
  }
  __builtin_amdgcn_s_barrier();
  __builtin_amdgcn_sched_barrier(0);

  f32x4 acc[4][4] = {};
  bfrag a_[4][2], b_lo[2][2], b_hi[2][2];

  for (int kt = 0; kt < NT; ++kt) {
    const int b = kt & 1;
    RD_A(a_, b);
    RD_B(b_lo, b, 0);
    if (kt + 1 < NT) STG_(B, Bs, bn, b ^ 1, 1, kt + 1, K);
    MFMA16(a_, b_lo, 0);
    __builtin_amdgcn_s_barrier();
    __builtin_amdgcn_sched_barrier(0);
    RD_B(b_hi, b, 1);
    if (kt + 2 < NT) {
      STG_(A, As, bm, b, 0, kt + 2, K);
      STG_(B, Bs, bn, b, 0, kt + 2, K);
    }
    MFMA16(a_, b_hi, 1);
    if (kt + 1 < NT) {
      if (kt + 2 < NT) asm volatile("s_waitcnt vmcnt(4)" ::: "memory");
      else             asm volatile("s_waitcnt vmcnt(0)" ::: "memory");
      __builtin_amdgcn_s_barrier();
      __builtin_amdgcn_sched_barrier(0);
    }
  }
#undef RD_A
#undef RD_B
#undef MFMA16
  const int rb = bm + wm * 64 + lg * 4, cb = bn + wn * 32 + lr;
#pragma unroll
  for (int i = 0; i < 4; ++i)
#pragma unroll
    for (int jh = 0; jh < 2; ++jh)
#pragma unroll
      for (int j = 0; j < 2; ++j)
#pragma unroll
        for (int r = 0; r < 4; ++r) {
          size_t idx = (size_t)(rb + i * 16 + r) * N + (cb + jh * 128 + j * 16);
          if (BF16OUT) ((short*)Cv)[idx] = f2bf(acc[i][jh * 2 + j][r]);
          else         ((float*)Cv)[idx] = acc[i][jh * 2 + j][r];
        }
}

// ---------- GEMM 256x256, BK=64, m201 8-phase (out-proj; 256 blocks = 1 rnd) ----------
// 8 waves (2M x 4N), per-wave 128x64 = acc[8][4] (43.7 FLOP/LDS-byte).
// Iter = 2 K-tiles (E=2t->buf0, O=2t+1->buf1), 8 phases, each stages 1 half-tile:
//   g0:A-h0(O)->b1  g1:A-h1(O)->b1  g2:B-h0(E+2)->b0  g3:B-h1(E+2)->b0 +vmcnt(4)
//   g4:A-h0(E+2)->b0 g5:A-h1(E+2)->b0 g6:B-h0(O+2)->b1 g7:B-h1(O+2)->b1 +vmcnt(4)
// Quad order per K-tile: (0,0),(0,1),(1,1),(1,0); B quads held in regs (g3: 0 reads).
// WAR: each staged region's last ds_read completes at the barrier 1+ phases before
// its stage slot. RAW: vmcnt(4) at g3 drains {B(O),A(O)}; at g7 drains tile E+2.
// Stage targets past NT clamped to tile 0 (region is dead -> harmless; counts uniform).
template<bool BF16OUT>
__global__ __launch_bounds__(512) void gemm256p(const short* __restrict__ A,
                                                const short* __restrict__ B,
                                                void* __restrict__ Cv,
                                                int M, int N, int K, int NBX) {
  __shared__ __align__(16) short As[2][256 * 64];   // 64 KB
  __shared__ __align__(16) short Bs[2][256 * 64];   // 64 KB
  const int tid = threadIdx.x, lane = tid & 63, wid = tid >> 6;
  const int lr = lane & 15, lg = lane >> 4;
  const int wm = wid >> 2, wn = wid & 3;
  // L2-compact map for 256 blocks, 16x16 tile grid
  const int orig = blockIdx.x;
  const int xc = orig & 7, o8 = orig >> 3;
  const int bmi = ((xc >> 1) << 2) + (o8 & 3);
  const int bni = (xc & 1) * (NBX >> 1) + (o8 >> 2);
  const int bm = bmi << 8, bn = bni << 8;
  const int NT = K >> 6;
  const int r0 = tid >> 3;
  const int c0 = tid & 7;
  const int csrc = c0 ^ (r0 & 7);

  int ch[2];
#pragma unroll
  for (int ks = 0; ks < 2; ++ks) ch[ks] = (((ks << 2) | lg) ^ (lr & 7)) << 4;
  const int aoff = (wm * 128 + lr) * 128;   // wave's A rows: wm*128..+127
  const int boff = (wn * 64 + lr) * 128;    // wave's B rows: wn*64..+63

#define RD_A8(dst, bb, ih)                                                       \
  do {                                                                           \
    const char* ab = (const char*)As[bb] + aoff + (ih) * 8192;                   \
    _Pragma("unroll") for (int i = 0; i < 4; ++i)                                \
      _Pragma("unroll") for (int ks = 0; ks < 2; ++ks)                           \
        dst[i][ks] = *(const bfrag*)(ab + i * 2048 + ch[ks]);                    \
  } while (0)
#define RD_B4(dst, bb, jh)                                                       \
  do {                                                                           \
    const char* bp = (const char*)Bs[bb] + boff + (jh) * 4096;                   \
    _Pragma("unroll") for (int j = 0; j < 2; ++j)                                \
      _Pragma("unroll") for (int ks = 0; ks < 2; ++ks)                           \
        dst[j][ks] = *(const bfrag*)(bp + j * 2048 + ch[ks]);                    \
  } while (0)
#define QUAD(af, bf, ih, jh)                                                     \
  do {                                                                           \
    __builtin_amdgcn_s_setprio(1);                                               \
    _Pragma("unroll") for (int ks = 0; ks < 2; ++ks)                             \
      _Pragma("unroll") for (int i = 0; i < 4; ++i)                              \
        _Pragma("unroll") for (int j = 0; j < 2; ++j)                            \
          acc[(ih) * 4 + i][(jh) * 2 + j] = __builtin_amdgcn_mfma_f32_16x16x32_bf16( \
              af[i][ks], bf[j][ks], acc[(ih) * 4 + i][(jh) * 2 + j], 0, 0, 0);   \
    __builtin_amdgcn_s_setprio(0);                                               \
  } while (0)
#define BARRIER() do { __builtin_amdgcn_s_barrier(); __builtin_amdgcn_sched_barrier(0); } while (0)

  // ---- prologue: tile0 (4 halves) + B(tile1) (2 halves); vmcnt(4) lands tile0 ----
  STG_(A, As, bm, 0, 0, 0, K); STG_(A, As, bm, 0, 1, 0, K);
  STG_(B, Bs, bn, 0, 0, 0, K); STG_(B, Bs, bn, 0, 1, 0, K);
  STG_(B, Bs, bn, 1, 0, 1, K); STG_(B, Bs, bn, 1, 1, 1, K);
  asm volatile("s_waitcnt vmcnt(4)" ::: "memory");
  BARRIER();

  f32x4 acc[8][4] = {};
  bfrag a_[4][2], b_lo[2][2], b_hi[2][2];
  const int NI = NT >> 1;   // NT even (K multiple of 128)

  for (int it = 0; it < NI; ++it) {
    const int O  = 2 * it + 1;
    int E2 = 2 * it + 2; if (E2 >= NT) E2 = 0;   // clamped (dead region, uniform counts)
    int O2 = 2 * it + 3; if (O2 >= NT) O2 = 0;
    // ---- g0: quad(0,0) of tile E (buf0); stage A-h0(O)->buf1 ----
    RD_A8(a_, 0, 0);
    RD_B4(b_lo, 0, 0);
    STG_(A, As, bm, 1, 0, O, K);
    BARRIER();
    asm volatile("s_waitcnt lgkmcnt(0)" ::: "memory");
    QUAD(a_, b_lo, 0, 0);
    BARRIER();
    // ---- g1: quad(0,1); stage A-h1(O)->buf1 ----
    RD_B4(b_hi, 0, 1);
    STG_(A, As, bm, 1, 1, O, K);
    BARRIER();
    asm volatile("s_waitcnt lgkmcnt(0)" ::: "memory");
    QUAD(a_, b_hi, 0, 1);
    BARRIER();
    // ---- g2: quad(1,1); stage B-h0(E2)->buf0 ----
    RD_A8(a_, 0, 1);
    STG_(B, Bs, bn, 0, 0, E2, K);
    BARRIER();
    asm volatile("s_waitcnt lgkmcnt(0)" ::: "memory");
    QUAD(a_, b_hi, 1, 1);
    BARRIER();
    // ---- g3: quad(1,0) (all regs); stage B-h1(E2)->buf0; vmcnt(4) lands tile O ----
    STG_(B, Bs, bn, 0, 1, E2, K);
    asm volatile("s_waitcnt vmcnt(4)" ::: "memory");
    BARRIER();
    QUAD(a_, b_lo, 1, 0);
    BARRIER();
    // ---- g4: quad(0,0) of tile O (buf1); stage A-h0(E2)->buf0 ----
    RD_A8(a_, 1, 0);
    RD_B4(b_lo, 1, 0);
    STG_(A, As, bm, 0, 0, E2, K);
    BARRIER();
    asm volatile("s_waitcnt lgkmcnt(0)" ::: "memory");
    QUAD(a_, b_lo, 0, 0);
    BARRIER();
    // ---- g5: quad(0,1); stage A-h1(E2)->buf0 ----
    RD_B4(b_hi, 1, 1);
    STG_(A, As, bm, 0, 1, E2, K);
    BARRIER();
    asm volatile("s_waitcnt lgkmcnt(0)" ::: "memory");
    QUAD(a_, b_hi, 0, 1);
    BARRIER();
    // ---- g6: quad(1,1); stage B-h0(O2)->buf1 ----
    RD_A8(a_, 1, 1);
    STG_(B, Bs, bn, 1, 0, O2, K);
    BARRIER();
    asm volatile("s_waitcnt lgkmcnt(0)" ::: "memory");
    QUAD(a_, b_hi, 1, 1);
    BARRIER();
    // ---- g7: quad(1,0); stage B-h1(O2)->buf1; vmcnt(4) lands tile E2 ----
    STG_(B, Bs, bn, 1, 1, O2, K);
    asm volatile("s_waitcnt vmcnt(4)" ::: "memory");
    BARRIER();
    QUAD(a_, b_lo, 1, 0);
    BARRIER();
  }
#undef RD_A8
#undef RD_B4
#undef QUAD
#undef BARRIER
  // ---- epilogue ----
  const int rb = bm + wm * 128 + lg * 4, cb = bn + wn * 64 + lr;
#pragma unroll
  for (int i = 0; i < 8; ++i)
#pragma unroll
    for (int j = 0; j < 4; ++j)
#pragma unroll
      for (int r = 0; r < 4; ++r) {
        size_t idx = (size_t)(rb + i * 16 + r) * N + (cb + j * 16);
        if (BF16OUT) ((short*)Cv)[idx] = f2bf(acc[i][j][r]);
        else         ((float*)Cv)[idx] = acc[i][j][r];
      }
}

// ---------- RoPE in-place (q heads 0..31, k heads 32..39) ----------
__global__ __launch_bounds__(256) void rope_k(short* __restrict__ qkv,
                                              const float* __restrict__ fcos,
                                              const float* __restrict__ fsin) {
  const int t = blockIdx.x;
  const int s = t & 2047;
  unsigned* row = (unsigned*)(qkv + (size_t)t * 6144);
  for (int p = threadIdx.x; p < 2560; p += 256) {
    const int h = p >> 6, i = p & 63;
    const int w = h * 64 + i;
    unsigned u = row[w];
    float a  = bf2f((short)(u & 0xffff));
    float b  = bf2f((short)(u >> 16));
    float c  = fcos[s * 64 + i], sn = fsin[s * 64 + i];
    float na = a * c - b * sn;
    float nb = a * sn + b * c;
    row[w] = ((unsigned)(unsigned short)f2bf(na)) |
             (((unsigned)(unsigned short)f2bf(nb)) << 16);
  }
}

// ---------- V transpose: qkv V-part [t][d] -> vt[b][kvh][d][s] ----------
__global__ __launch_bounds__(256) void vtrans(const short* __restrict__ qkv,
                                              short* __restrict__ vt) {
  const int sb = blockIdx.x, kvh = blockIdx.y, b = blockIdx.z;
  __shared__ short T[64][136];
  const int tid = threadIdx.x;
#pragma unroll
  for (int it = 0; it < 4; ++it) {
    int c = it * 256 + tid;
    int r = c >> 4, dc = c & 15;
    s16x8 v = *(const s16x8*)(qkv + (size_t)(b * 2048 + sb * 64 + r) * 6144
                              + 5120 + kvh * 128 + dc * 8);
    *(s16x8*)&T[r][dc * 8] = v;
  }
  __syncthreads();
#pragma unroll
  for (int it = 0; it < 4; ++it) {
    int c = it * 256 + tid;
    int d = c >> 3, sc = c & 7;
    s16x8 v;
#pragma unroll
    for (int j = 0; j < 8; ++j) v[j] = T[sc * 8 + j][d];
    *(s16x8*)(vt + (size_t)((b * 8 + kvh) * 128 + d) * 2048 + sb * 64 + sc * 8) = v;
  }
}

// ---------- Flash attention, m214 structure; qb<->z balance flip ----------
__global__ __launch_bounds__(512, 2) void fattn2(const short* __restrict__ qkv,
                                                 const short* __restrict__ vt,
                                                 short* __restrict__ ao) {
  const int b = blockIdx.z, h = blockIdx.y;
  const int qb = b ? (int)gridDim.x - 1 - blockIdx.x : blockIdx.x;
  const int kvh = h >> 2;
  const int tid = threadIdx.x;
  const int lane = tid & 63, wid = tid >> 6;
  const int l31 = lane & 31, hi = lane >> 5;
  __shared__ __align__(16) short Ks[2][64 * 128];
  __shared__ __align__(16) short Vs[2][128 * 64];

  const int q0w   = qb * 256 + wid * 32;
  const int qg    = q0w + l31;
  const int tmaxw = q0w >> 6;
  const int NT    = 4 * qb + 4;

  bfrag qf[8];
  {
    const short* qp = qkv + (size_t)(b * 2048 + qg) * 6144 + h * 128 + hi * 8;
#pragma unroll
    for (int kk = 0; kk < 8; ++kk) qf[kk] = *(const bfrag*)(qp + kk * 16);
  }

  const int kr0 = tid >> 4, kcc = tid & 15;
  const int vd0 = tid >> 3, vkc = tid & 7;
  const int kro[2] = { kr0, kr0 + 32 };
  const int vdo[2] = { vd0, vd0 + 64 };
  int kldst[2], vldst[2];
#pragma unroll
  for (int i = 0; i < 2; ++i) {
    kldst[i] = (kro[i] * 256 + kcc * 16) ^ ((kro[i] & 7) << 4);
    vldst[i] = (vdo[i] * 128 + vkc * 16) ^ ((vdo[i] & 7) << 4);
  }
  const short* base_k = qkv + (size_t)(b * 2048) * 6144 + 4096 + kvh * 128;
  const short* base_v = vt + (size_t)((b * 8 + kvh) * 128) * 2048;

  {
    s16x8 kr_[2], vr_[2];
#pragma unroll
    for (int i = 0; i < 2; ++i) {
      kr_[i] = *(const s16x8*)(base_k + (size_t)kro[i] * 6144 + kcc * 8);
      vr_[i] = *(const s16x8*)(base_v + (size_t)vdo[i] * 2048 + vkc * 8);
    }
#pragma unroll
    for (int i = 0; i < 2; ++i) {
      *(s16x8*)((char*)Ks[0] + kldst[i]) = kr_[i];
      *(s16x8*)((char*)Vs[0] + vldst[i]) = vr_[i];
    }
  }
  __syncthreads();

  f32x16 o[4] = {};
  float m = -3.0e38f, l = 0.f;
  const float c0 = 0.08838834764831845f * 1.4426950408889634f;
  const int  sw = (l31 & 7) << 4;

  for (int t = 0; t < NT; ++t) {
    const int cur = t & 1;
    s16x8 kr_[2], vr_[2];
    const bool pf = (t + 1 < NT);
    if (pf) {
#pragma unroll
      for (int i = 0; i < 2; ++i) {
        kr_[i] = *(const s16x8*)(base_k + (size_t)((t + 1) * 64 + kro[i]) * 6144 + kcc * 8);
        vr_[i] = *(const s16x8*)(base_v + (size_t)vdo[i] * 2048 + (t + 1) * 64 + vkc * 8);
      }
    }
    if (t <= tmaxw) {
      f32x16 st[2] = {};
      {
        const char* kb = (const char*)Ks[cur] + l31 * 256;
        __builtin_amdgcn_s_setprio(1);
#pragma unroll
        for (int kk = 0; kk < 8; ++kk) {
          const int ko = (kk * 32 + hi * 16) ^ sw;
          bfrag kf0 = *(const bfrag*)(kb + ko);
          bfrag kf1 = *(const bfrag*)(kb + 8192 + ko);
          st[0] = __builtin_amdgcn_mfma_f32_32x32x16_bf16(kf0, qf[kk], st[0], 0, 0, 0);
          st[1] = __builtin_amdgcn_mfma_f32_32x32x16_bf16(kf1, qf[kk], st[1], 0, 0, 0);
        }
        __builtin_amdgcn_s_setprio(0);
      }
      if (t == tmaxw) {
        const int kb0 = t * 64 + 4 * hi;
#pragma unroll
        for (int kt = 0; kt < 2; ++kt)
#pragma unroll
          for (int r = 0; r < 16; ++r) {
            int k = kb0 + kt * 32 + (r & 3) + 8 * (r >> 2);
            if (k > qg) st[kt][r] = -3.0e38f;
          }
      }
      float mt = -3.0e38f;
#pragma unroll
      for (int kt = 0; kt < 2; ++kt)
#pragma unroll
        for (int r = 0; r < 16; ++r) mt = fmaxf(mt, st[kt][r]);
      mt = fmaxf(mt, __shfl_xor(mt, 32, 64));
      if (!__all((mt - m) * c0 <= 8.0f)) {
        float nm = fmaxf(m, mt);
        float fe = exp2f((m - nm) * c0);
        m = nm;
        l *= fe;
#pragma unroll
        for (int dt = 0; dt < 4; ++dt)
#pragma unroll
          for (int r = 0; r < 16; ++r) o[dt][r] *= fe;
      }
      const float mc = m * c0;
      float ps = 0.f;
#pragma unroll
      for (int kt = 0; kt < 2; ++kt)
#pragma unroll
        for (int r = 0; r < 16; ++r) {
          float p = exp2f(st[kt][r] * c0 - mc);
          st[kt][r] = p;
          ps += p;
        }
      ps += __shfl_xor(ps, 32, 64);
      l += ps;
      bfrag pfr[4];
#pragma unroll
      for (int kt = 0; kt < 2; ++kt) {
        u32x2 a0 = __builtin_amdgcn_permlane32_swap(cvtpk(st[kt][0],  st[kt][1]),
                                                    cvtpk(st[kt][4],  st[kt][5]),  0, 0);
        u32x2 a1 = __builtin_amdgcn_permlane32_swap(cvtpk(st[kt][2],  st[kt][3]),
                                                    cvtpk(st[kt][6],  st[kt][7]),  0, 0);
        u32x2 b0 = __builtin_amdgcn_permlane32_swap(cvtpk(st[kt][8],  st[kt][9]),
                                                    cvtpk(st[kt][12], st[kt][13]), 0, 0);
        u32x2 b1 = __builtin_amdgcn_permlane32_swap(cvtpk(st[kt][10], st[kt][11]),
                                                    cvtpk(st[kt][14], st[kt][15]), 0, 0);
        u32x4 w0 = { a0.x, a1.x, a0.y, a1.y };
        u32x4 w1 = { b0.x, b1.x, b0.y, b1.y };
        pfr[kt * 2]     = __builtin_bit_cast(bfrag, w0);
        pfr[kt * 2 + 1] = __builtin_bit_cast(bfrag, w1);
      }
      __builtin_amdgcn_s_setprio(1);
#pragma unroll
      for (int ks = 0; ks < 4; ++ks) {
        const char* vb = (const char*)Vs[cur] + l31 * 128 + ((ks * 32 + hi * 16) ^ sw);
#pragma unroll
        for (int dt = 0; dt < 4; ++dt) {
          bfrag vf = *(const bfrag*)(vb + dt * 4096);
          o[dt] = __builtin_amdgcn_mfma_f32_32x32x16_bf16(vf, pfr[ks], o[dt], 0, 0, 0);
        }
      }
      __builtin_amdgcn_s_setprio(0);
    }
    __syncthreads();
    if (pf) {
#pragma unroll
      for (int i = 0; i < 2; ++i) {
        *(s16x8*)((char*)Ks[cur ^ 1] + kldst[i]) = kr_[i];
        *(s16x8*)((char*)Vs[cur ^ 1] + vldst[i]) = vr_[i];
      }
    }
    __syncthreads();
  }
  const float linv = 1.f / l;
  short* aop = ao + (size_t)(b * 2048 + qg) * 4096 + h * 128 + 4 * hi;
#pragma unroll
  for (int dt = 0; dt < 4; ++dt)
#pragma unroll
    for (int r = 0; r < 16; ++r) {
      int d = dt * 32 + (r & 3) + 8 * (r >> 2);
      aop[d] = f2bf(o[dt][r] * linv);
    }
}

// ---------- launch ----------
extern "C" void kernel_launch(void* const* d_in, const int* in_sizes, int n_in,
                              void* d_out, int out_size, void* d_ws, size_t ws_size,
                              hipStream_t stream) {
  const float* x  = (const float*)d_in[0];
  const float* wq = (const float*)d_in[1];
  const float* wk = (const float*)d_in[2];
  const float* wv = (const float*)d_in[3];
  const float* wo = (const float*)d_in[4];
  const float* fc = (const float*)d_in[7];
  const float* fs = (const float*)d_in[8];

  char* ws = (char*)d_ws;
  short* xb    = (short*)(ws);                    // [4096][4096] bf16; reused as ao
  short* ao    = xb;
  short* wqkvb = (short*)(ws + 33554432ull);      // [6144][4096] bf16
  short* qkv   = (short*)(ws + 83886080ull);      // [4096][6144] bf16
  short* vt    = (short*)(ws + 134217728ull);     // [2][8][128][2048] bf16
  short* wob   = (short*)(ws + 167772160ull);     // [4096][4096] bf16

  cvt4<<<40960, 256, 0, stream>>>(x, wq, wk, wv,
                                  xb, wqkvb, wqkvb + 16777216, wqkvb + 20971520);
  gemm128n<true ><<<768, 512, 0, stream>>>(xb, wqkvb, qkv, 4096, 6144, 4096, 24);
  rope_k<<<4096, 256, 0, stream>>>(qkv, fc, fs);
  vtrans<<<dim3(32, 8, 2), 256, 0, stream>>>(qkv, vt);
  cvt_f32_bf16<<<16384, 256, 0, stream>>>(wo, wob, 4194304);
  fattn2<<<dim3(8, 32, 2), 512, 0, stream>>>(qkv, vt, ao);
  gemm256p<false><<<256, 512, 0, stream>>>(ao, wob, (float*)d_out, 4096, 4096, 4096, 16);
}

// Round 14
// 478.951 us; speedup vs baseline: 1.4479x; 1.0271x over previous
//
#include <hip/hip_runtime.h>
#include <hip/hip_bf16.h>
#include <math.h>

// ---------- types ----------
typedef __attribute__((ext_vector_type(8)))  __bf16 bfrag;   // MFMA A/B operand (8 bf16)
typedef __attribute__((ext_vector_type(4)))  float  f32x4;
typedef __attribute__((ext_vector_type(16))) float  f32x16;  // 32x32 MFMA C/D
typedef __attribute__((ext_vector_type(8)))  short  s16x8;
typedef __attribute__((ext_vector_type(4)))  short  s16x4;
typedef __attribute__((ext_vector_type(2)))  unsigned u32x2;
typedef __attribute__((ext_vector_type(4)))  unsigned u32x4;

__device__ __forceinline__ short f2bf(float f) {
  return (short)__builtin_bit_cast(unsigned short, (__bf16)f);
}
__device__ __forceinline__ float bf2f(short s) {
  return (float)__builtin_bit_cast(__bf16, (unsigned short)s);
}
__device__ __forceinline__ unsigned cvtpk(float lo, float hi_) {
  unsigned r;
  asm("v_cvt_pk_bf16_f32 %0, %1, %2" : "=v"(r) : "v"(lo), "v"(hi_));
  return r;
}
__device__ __forceinline__ void gll16(const void* g, void* l) {
  __builtin_amdgcn_global_load_lds((const __attribute__((address_space(1))) void*)g,
                                   (__attribute__((address_space(3))) void*)l, 16, 0, 0);
}

// ---------- f32 -> bf16 converts (nontemporal input reads: read-once data) ----------
__global__ __launch_bounds__(256) void cvt_f32_bf16(const float* __restrict__ in,
                                                    short* __restrict__ out, int n4) {
  int i = blockIdx.x * 256 + threadIdx.x;
  if (i >= n4) return;
  f32x4 v = __builtin_nontemporal_load((const f32x4*)in + i);
  s16x4 o;
  o.x = f2bf(v.x); o.y = f2bf(v.y); o.z = f2bf(v.z); o.w = f2bf(v.w);
  ((s16x4*)out)[i] = o;
}

__global__ __launch_bounds__(256) void cvt4(const float* __restrict__ x,
                                            const float* __restrict__ wq,
                                            const float* __restrict__ wk,
                                            const float* __restrict__ wv,
                                            short* __restrict__ xb,
                                            short* __restrict__ wqb,
                                            short* __restrict__ wkb,
                                            short* __restrict__ wvb) {
  const int b = blockIdx.x;
  const float* in; short* out; int base;
  if (b < 16384)      { in = x;  out = xb;  base = 0; }
  else if (b < 32768) { in = wq; out = wqb; base = 16384 * 256; }
  else if (b < 36864) { in = wk; out = wkb; base = 32768 * 256; }
  else                { in = wv; out = wvb; base = 36864 * 256; }
  const int idx = b * 256 + threadIdx.x - base;
  f32x4 v = __builtin_nontemporal_load((const f32x4*)in + idx);
  s16x4 o;
  o.x = f2bf(v.x); o.y = f2bf(v.y); o.z = f2bf(v.z); o.w = f2bf(v.w);
  ((s16x4*)out)[idx] = o;
}

// ---------- shared staging macro (half-tile = 128 rows x 64 cols, 2 gll16/thr) ----------
#define STG_(OP, OPs, boff, bb, hh, kt_, Kd)                                     \
  do {                                                                           \
    _Pragma("unroll")                                                            \
    for (int s = 0; s < 2; ++s)                                                  \
      gll16(OP + (size_t)(boff + (hh) * 128 + s * 64 + r0) * Kd + (kt_) * 64 + csrc * 8, \
            (char*)OPs[bb] + ((hh) * 128 + s * 64 + wid * 8) * 128);             \
  } while (0)

// ---------- GEMM 128x256 tile (QKV; 768 blocks) + FUSED RoPE epilogue ----------
// RoPE pairs (col 2i,2i+1) live in lanes (lr, lr^1) of the same row:
// out_even = a*c - b*sn, out_odd = a*sn + b*c  via one __shfl_xor(.,1).
// i_idx = (wn*32+j*16+lr)>>1 (jh-independent); s = row&2047; rope iff bn<5120
// (Q/K cols 0..5119; block cols span one 256-aligned bni -> uniform branch).
template<bool ROPE>
__global__ __launch_bounds__(512) void gemm128n(const short* __restrict__ A,
                                                const short* __restrict__ B,
                                                short* __restrict__ C,
                                                int M, int N, int K, int NBX,
                                                const float* __restrict__ fcos,
                                                const float* __restrict__ fsin) {
  __shared__ __align__(16) short As[2][128 * 64];
  __shared__ __align__(16) short Bs[2][256 * 64];
  const int tid = threadIdx.x, lane = tid & 63, wid = tid >> 6;
  const int lr = lane & 15, lg = lane >> 4;
  const int wm = wid >> 2, wn = wid & 3;
  const int orig = blockIdx.x;
  const int xc = orig & 7, o8 = orig >> 3;
  const int s8 = o8 >> 5, t8 = o8 & 31;
  const int bmi = ((xc >> 1) << 3) + (t8 >> 2);
  const int bni = (xc & 1) * (NBX >> 1) + (s8 << 2) + (t8 & 3);
  const int bm = bmi << 7, bn = bni << 8;
  const int NT = K >> 6;
  const int r0 = tid >> 3;
  const int c0 = tid & 7;
  const int csrc = c0 ^ (r0 & 7);

  int ch[2];
#pragma unroll
  for (int ks = 0; ks < 2; ++ks) ch[ks] = (((ks << 2) | lg) ^ (lr & 7)) << 4;
  const int aoff  = (wm * 64 + lr) * 128;
  const int boff2 = (wn * 32 + lr) * 128;

#define RD_A(dst, bb)                                                            \
  do {                                                                           \
    const char* ab = (const char*)As[bb] + aoff;                                 \
    _Pragma("unroll") for (int i = 0; i < 4; ++i)                                \
      _Pragma("unroll") for (int ks = 0; ks < 2; ++ks)                           \
        dst[i][ks] = *(const bfrag*)(ab + i * 2048 + ch[ks]);                    \
  } while (0)
#define RD_B(dst, bb, jh)                                                        \
  do {                                                                           \
    const char* bp = (const char*)Bs[bb] + boff2 + (jh) * 16384;                 \
    _Pragma("unroll") for (int j = 0; j < 2; ++j)                                \
      _Pragma("unroll") for (int ks = 0; ks < 2; ++ks)                           \
        dst[j][ks] = *(const bfrag*)(bp + j * 2048 + ch[ks]);                    \
  } while (0)
#define MFMA16(af, bf, jh)                                                       \
  do {                                                                           \
    __builtin_amdgcn_s_setprio(1);                                               \
    _Pragma("unroll") for (int ks = 0; ks < 2; ++ks)                             \
      _Pragma("unroll") for (int i = 0; i < 4; ++i)                              \
        _Pragma("unroll") for (int j = 0; j < 2; ++j)                            \
          acc[i][(jh) * 2 + j] = __builtin_amdgcn_mfma_f32_16x16x32_bf16(        \
              af[i][ks], bf[j][ks], acc[i][(jh) * 2 + j], 0, 0, 0);              \
    __builtin_amdgcn_s_setprio(0);                                               \
  } while (0)

  STG_(A, As, bm, 0, 0, 0, K);
  STG_(B, Bs, bn, 0, 0, 0, K);
  STG_(B, Bs, bn, 0, 1, 0, K);
  if (NT > 1) {
    STG_(A, As, bm, 1, 0, 1, K);
    STG_(B, Bs, bn, 1, 0, 1, K);
    asm volatile("s_waitcnt vmcnt(4)" ::: "memory");
  } else {
    asm volatile("s_waitcnt vmcnt(0)" ::: "memory");
  }
  __builtin_amdgcn_s_barrier();
  __builtin_amdgcn_sched_barrier(0);

  f32x4 acc[4][4] = {};
  bfrag a_[4][2], b_lo[2][2], b_hi[2][2];

  for (int kt = 0; kt < NT; ++kt) {
    const int b = kt & 1;
    RD_A(a_, b);
    RD_B(b_lo, b, 0);
    if (kt + 1 < NT) STG_(B, Bs, bn, b ^ 1, 1, kt + 1, K);
    MFMA16(a_, b_lo, 0);
    __builtin_amdgcn_s_barrier();
    __builtin_amdgcn_sched_barrier(0);
    RD_B(b_hi, b, 1);
    if (kt + 2 < NT) {
      STG_(A, As, bm, b, 0, kt + 2, K);
      STG_(B, Bs, bn, b, 0, kt + 2, K);
    }
    MFMA16(a_, b_hi, 1);
    if (kt + 1 < NT) {
      if (kt + 2 < NT) asm volatile("s_waitcnt vmcnt(4)" ::: "memory");
      else             asm volatile("s_waitcnt vmcnt(0)" ::: "memory");
      __builtin_amdgcn_s_barrier();
      __builtin_amdgcn_sched_barrier(0);
    }
  }
#undef RD_A
#undef RD_B
#undef MFMA16
  // ---- epilogue (optionally fused RoPE) ----
  const int rb = bm + wm * 64 + lg * 4, cb = bn + wn * 32 + lr;
  if (ROPE && bn < 5120) {
    const bool odd = (lr & 1) != 0;
#pragma unroll
    for (int j = 0; j < 2; ++j) {
      const int iidx = (wn * 32 + j * 16 + lr) >> 1;
#pragma unroll
      for (int i = 0; i < 4; ++i)
#pragma unroll
        for (int r = 0; r < 4; ++r) {
          const int row = rb + i * 16 + r;
          const int sp = row & 2047;
          const float c  = fcos[sp * 64 + iidx];
          const float sn = fsin[sp * 64 + iidx];
#pragma unroll
          for (int jh = 0; jh < 2; ++jh) {
            float own = acc[i][jh * 2 + j][r];
            float par = __shfl_xor(own, 1, 64);
            float out = odd ? (par * sn + own * c) : (own * c - par * sn);
            C[(size_t)row * N + (cb + jh * 128 + j * 16)] = f2bf(out);
          }
        }
    }
  } else {
#pragma unroll
    for (int i = 0; i < 4; ++i)
#pragma unroll
      for (int jh = 0; jh < 2; ++jh)
#pragma unroll
        for (int j = 0; j < 2; ++j)
#pragma unroll
          for (int r = 0; r < 4; ++r)
            C[(size_t)(rb + i * 16 + r) * N + (cb + jh * 128 + j * 16)] =
                f2bf(acc[i][jh * 2 + j][r]);
  }
}

// ---------- GEMM 256x256, BK=64, m201 8-phase (out-proj; 256 blocks) ----------
template<bool BF16OUT>
__global__ __launch_bounds__(512) void gemm256p(const short* __restrict__ A,
                                                const short* __restrict__ B,
                                                void* __restrict__ Cv,
                                                int M, int N, int K, int NBX) {
  __shared__ __align__(16) short As[2][256 * 64];   // 64 KB
  __shared__ __align__(16) short Bs[2][256 * 64];   // 64 KB
  const int tid = threadIdx.x, lane = tid & 63, wid = tid >> 6;
  const int lr = lane & 15, lg = lane >> 4;
  const int wm = wid >> 2, wn = wid & 3;
  const int orig = blockIdx.x;
  const int xc = orig & 7, o8 = orig >> 3;
  const int bmi = ((xc >> 1) << 2) + (o8 & 3);
  const int bni = (xc & 1) * (NBX >> 1) + (o8 >> 2);
  const int bm = bmi << 8, bn = bni << 8;
  const int NT = K >> 6;
  const int r0 = tid >> 3;
  const int c0 = tid & 7;
  const int csrc = c0 ^ (r0 & 7);

  int ch[2];
#pragma unroll
  for (int ks = 0; ks < 2; ++ks) ch[ks] = (((ks << 2) | lg) ^ (lr & 7)) << 4;
  const int aoff = (wm * 128 + lr) * 128;
  const int boff = (wn * 64 + lr) * 128;

#define RD_A8(dst, bb, ih)                                                       \
  do {                                                                           \
    const char* ab = (const char*)As[bb] + aoff + (ih) * 8192;                   \
    _Pragma("unroll") for (int i = 0; i < 4; ++i)                                \
      _Pragma("unroll") for (int ks = 0; ks < 2; ++ks)                           \
        dst[i][ks] = *(const bfrag*)(ab + i * 2048 + ch[ks]);                    \
  } while (0)
#define RD_B4(dst, bb, jh)                                                       \
  do {                                                                           \
    const char* bp = (const char*)Bs[bb] + boff + (jh) * 4096;                   \
    _Pragma("unroll") for (int j = 0; j < 2; ++j)                                \
      _Pragma("unroll") for (int ks = 0; ks < 2; ++ks)                           \
        dst[j][ks] = *(const bfrag*)(bp + j * 2048 + ch[ks]);                    \
  } while (0)
#define QUAD(af, bf, ih, jh)                                                     \
  do {                                                                           \
    __builtin_amdgcn_s_setprio(1);                                               \
    _Pragma("unroll") for (int ks = 0; ks < 2; ++ks)                             \
      _Pragma("unroll") for (int i = 0; i < 4; ++i)                              \
        _Pragma("unroll") for (int j = 0; j < 2; ++j)                            \
          acc[(ih) * 4 + i][(jh) * 2 + j] = __builtin_amdgcn_mfma_f32_16x16x32_bf16( \
              af[i][ks], bf[j][ks], acc[(ih) * 4 + i][(jh) * 2 + j], 0, 0, 0);   \
    __builtin_amdgcn_s_setprio(0);                                               \
  } while (0)
#define BARRIER() do { __builtin_amdgcn_s_barrier(); __builtin_amdgcn_sched_barrier(0); } while (0)

  STG_(A, As, bm, 0, 0, 0, K); STG_(A, As, bm, 0, 1, 0, K);
  STG_(B, Bs, bn, 0, 0, 0, K); STG_(B, Bs, bn, 0, 1, 0, K);
  STG_(B, Bs, bn, 1, 0, 1, K); STG_(B, Bs, bn, 1, 1, 1, K);
  asm volatile("s_waitcnt vmcnt(4)" ::: "memory");
  BARRIER();

  f32x4 acc[8][4] = {};
  bfrag a_[4][2], b_lo[2][2], b_hi[2][2];
  const int NI = NT >> 1;

  for (int it = 0; it < NI; ++it) {
    const int O  = 2 * it + 1;
    int E2 = 2 * it + 2; if (E2 >= NT) E2 = 0;
    int O2 = 2 * it + 3; if (O2 >= NT) O2 = 0;
    RD_A8(a_, 0, 0);
    RD_B4(b_lo, 0, 0);
    STG_(A, As, bm, 1, 0, O, K);
    BARRIER();
    asm volatile("s_waitcnt lgkmcnt(0)" ::: "memory");
    QUAD(a_, b_lo, 0, 0);
    BARRIER();
    RD_B4(b_hi, 0, 1);
    STG_(A, As, bm, 1, 1, O, K);
    BARRIER();
    asm volatile("s_waitcnt lgkmcnt(0)" ::: "memory");
    QUAD(a_, b_hi, 0, 1);
    BARRIER();
    RD_A8(a_, 0, 1);
    STG_(B, Bs, bn, 0, 0, E2, K);
    BARRIER();
    asm volatile("s_waitcnt lgkmcnt(0)" ::: "memory");
    QUAD(a_, b_hi, 1, 1);
    BARRIER();
    STG_(B, Bs, bn, 0, 1, E2, K);
    asm volatile("s_waitcnt vmcnt(4)" ::: "memory");
    BARRIER();
    QUAD(a_, b_lo, 1, 0);
    BARRIER();
    RD_A8(a_, 1, 0);
    RD_B4(b_lo, 1, 0);
    STG_(A, As, bm, 0, 0, E2, K);
    BARRIER();
    asm volatile("s_waitcnt lgkmcnt(0)" ::: "memory");
    QUAD(a_, b_lo, 0, 0);
    BARRIER();
    RD_B4(b_hi, 1, 1);
    STG_(A, As, bm, 0, 1, E2, K);
    BARRIER();
    asm volatile("s_waitcnt lgkmcnt(0)" ::: "memory");
    QUAD(a_, b_hi, 0, 1);
    BARRIER();
    RD_A8(a_, 1, 1);
    STG_(B, Bs, bn, 1, 0, O2, K);
    BARRIER();
    asm volatile("s_waitcnt lgkmcnt(0)" ::: "memory");
    QUAD(a_, b_hi, 1, 1);
    BARRIER();
    STG_(B, Bs, bn, 1, 1, O2, K);
    asm volatile("s_waitcnt vmcnt(4)" ::: "memory");
    BARRIER();
    QUAD(a_, b_lo, 1, 0);
    BARRIER();
  }
#undef RD_A8
#undef RD_B4
#undef QUAD
#undef BARRIER
  const int rb = bm + wm * 128 + lg * 4, cb = bn + wn * 64 + lr;
#pragma unroll
  for (int i = 0; i < 8; ++i)
#pragma unroll
    for (int j = 0; j < 4; ++j)
#pragma unroll
      for (int r = 0; r < 4; ++r) {
        size_t idx = (size_t)(rb + i * 16 + r) * N + (cb + j * 16);
        if (BF16OUT) ((short*)Cv)[idx] = f2bf(acc[i][j][r]);
        else         ((float*)Cv)[idx] = acc[i][j][r];
      }
}

// ---------- V transpose: qkv V-part [t][d] -> vt[b][kvh][d][s] ----------
__global__ __launch_bounds__(256) void vtrans(const short* __restrict__ qkv,
                                              short* __restrict__ vt) {
  const int sb = blockIdx.x, kvh = blockIdx.y, b = blockIdx.z;
  __shared__ short T[64][136];
  const int tid = threadIdx.x;
#pragma unroll
  for (int it = 0; it < 4; ++it) {
    int c = it * 256 + tid;
    int r = c >> 4, dc = c & 15;
    s16x8 v = *(const s16x8*)(qkv + (size_t)(b * 2048 + sb * 64 + r) * 6144
                              + 5120 + kvh * 128 + dc * 8);
    *(s16x8*)&T[r][dc * 8] = v;
  }
  __syncthreads();
#pragma unroll
  for (int it = 0; it < 4; ++it) {
    int c = it * 256 + tid;
    int d = c >> 3, sc = c & 7;
    s16x8 v;
#pragma unroll
    for (int j = 0; j < 8; ++j) v[j] = T[sc * 8 + j][d];
    *(s16x8*)(vt + (size_t)((b * 8 + kvh) * 128 + d) * 2048 + sb * 64 + sc * 8) = v;
  }
}

// ---------- Flash attention, m214 structure; qb<->z balance flip ----------
__global__ __launch_bounds__(512, 2) void fattn2(const short* __restrict__ qkv,
                                                 const short* __restrict__ vt,
                                                 short* __restrict__ ao) {
  const int b = blockIdx.z, h = blockIdx.y;
  const int qb = b ? (int)gridDim.x - 1 - blockIdx.x : blockIdx.x;
  const int kvh = h >> 2;
  const int tid = threadIdx.x;
  const int lane = tid & 63, wid = tid >> 6;
  const int l31 = lane & 31, hi = lane >> 5;
  __shared__ __align__(16) short Ks[2][64 * 128];
  __shared__ __align__(16) short Vs[2][128 * 64];

  const int q0w   = qb * 256 + wid * 32;
  const int qg    = q0w + l31;
  const int tmaxw = q0w >> 6;
  const int NT    = 4 * qb + 4;

  bfrag qf[8];
  {
    const short* qp = qkv + (size_t)(b * 2048 + qg) * 6144 + h * 128 + hi * 8;
#pragma unroll
    for (int kk = 0; kk < 8; ++kk) qf[kk] = *(const bfrag*)(qp + kk * 16);
  }

  const int kr0 = tid >> 4, kcc = tid & 15;
  const int vd0 = tid >> 3, vkc = tid & 7;
  const int kro[2] = { kr0, kr0 + 32 };
  const int vdo[2] = { vd0, vd0 + 64 };
  int kldst[2], vldst[2];
#pragma unroll
  for (int i = 0; i < 2; ++i) {
    kldst[i] = (kro[i] * 256 + kcc * 16) ^ ((kro[i] & 7) << 4);
    vldst[i] = (vdo[i] * 128 + vkc * 16) ^ ((vdo[i] & 7) << 4);
  }
  const short* base_k = qkv + (size_t)(b * 2048) * 6144 + 4096 + kvh * 128;
  const short* base_v = vt + (size_t)((b * 8 + kvh) * 128) * 2048;

  {
    s16x8 kr_[2], vr_[2];
#pragma unroll
    for (int i = 0; i < 2; ++i) {
      kr_[i] = *(const s16x8*)(base_k + (size_t)kro[i] * 6144 + kcc * 8);
      vr_[i] = *(const s16x8*)(base_v + (size_t)vdo[i] * 2048 + vkc * 8);
    }
#pragma unroll
    for (int i = 0; i < 2; ++i) {
      *(s16x8*)((char*)Ks[0] + kldst[i]) = kr_[i];
      *(s16x8*)((char*)Vs[0] + vldst[i]) = vr_[i];
    }
  }
  __syncthreads();

  f32x16 o[4] = {};
  float m = -3.0e38f, l = 0.f;
  const float c0 = 0.08838834764831845f * 1.4426950408889634f;
  const int  sw = (l31 & 7) << 4;

  for (int t = 0; t < NT; ++t) {
    const int cur = t & 1;
    s16x8 kr_[2], vr_[2];
    const bool pf = (t + 1 < NT);
    if (pf) {
#pragma unroll
      for (int i = 0; i < 2; ++i) {
        kr_[i] = *(const s16x8*)(base_k + (size_t)((t + 1) * 64 + kro[i]) * 6144 + kcc * 8);
        vr_[i] = *(const s16x8*)(base_v + (size_t)vdo[i] * 2048 + (t + 1) * 64 + vkc * 8);
      }
    }
    if (t <= tmaxw) {
      f32x16 st[2] = {};
      {
        const char* kb = (const char*)Ks[cur] + l31 * 256;
        __builtin_amdgcn_s_setprio(1);
#pragma unroll
        for (int kk = 0; kk < 8; ++kk) {
          const int ko = (kk * 32 + hi * 16) ^ sw;
          bfrag kf0 = *(const bfrag*)(kb + ko);
          bfrag kf1 = *(const bfrag*)(kb + 8192 + ko);
          st[0] = __builtin_amdgcn_mfma_f32_32x32x16_bf16(kf0, qf[kk], st[0], 0, 0, 0);
          st[1] = __builtin_amdgcn_mfma_f32_32x32x16_bf16(kf1, qf[kk], st[1], 0, 0, 0);
        }
        __builtin_amdgcn_s_setprio(0);
      }
      if (t == tmaxw) {
        const int kb0 = t * 64 + 4 * hi;
#pragma unroll
        for (int kt = 0; kt < 2; ++kt)
#pragma unroll
          for (int r = 0; r < 16; ++r) {
            int k = kb0 + kt * 32 + (r & 3) + 8 * (r >> 2);
            if (k > qg) st[kt][r] = -3.0e38f;
          }
      }
      float mt = -3.0e38f;
#pragma unroll
      for (int kt = 0; kt < 2; ++kt)
#pragma unroll
        for (int r = 0; r < 16; ++r) mt = fmaxf(mt, st[kt][r]);
      mt = fmaxf(mt, __shfl_xor(mt, 32, 64));
      if (!__all((mt - m) * c0 <= 8.0f)) {
        float nm = fmaxf(m, mt);
        float fe = exp2f((m - nm) * c0);
        m = nm;
        l *= fe;
#pragma unroll
        for (int dt = 0; dt < 4; ++dt)
#pragma unroll
          for (int r = 0; r < 16; ++r) o[dt][r] *= fe;
      }
      const float mc = m * c0;
      float ps = 0.f;
#pragma unroll
      for (int kt = 0; kt < 2; ++kt)
#pragma unroll
        for (int r = 0; r < 16; ++r) {
          float p = exp2f(st[kt][r] * c0 - mc);
          st[kt][r] = p;
          ps += p;
        }
      ps += __shfl_xor(ps, 32, 64);
      l += ps;
      bfrag pfr[4];
#pragma unroll
      for (int kt = 0; kt < 2; ++kt) {
        u32x2 a0 = __builtin_amdgcn_permlane32_swap(cvtpk(st[kt][0],  st[kt][1]),
                                                    cvtpk(st[kt][4],  st[kt][5]),  0, 0);
        u32x2 a1 = __builtin_amdgcn_permlane32_swap(cvtpk(st[kt][2],  st[kt][3]),
                                                    cvtpk(st[kt][6],  st[kt][7]),  0, 0);
        u32x2 b0 = __builtin_amdgcn_permlane32_swap(cvtpk(st[kt][8],  st[kt][9]),
                                                    cvtpk(st[kt][12], st[kt][13]), 0, 0);
        u32x2 b1 = __builtin_amdgcn_permlane32_swap(cvtpk(st[kt][10], st[kt][11]),
                                                    cvtpk(st[kt][14], st[kt][15]), 0, 0);
        u32x4 w0 = { a0.x, a1.x, a0.y, a1.y };
        u32x4 w1 = { b0.x, b1.x, b0.y, b1.y };
        pfr[kt * 2]     = __builtin_bit_cast(bfrag, w0);
        pfr[kt * 2 + 1] = __builtin_bit_cast(bfrag, w1);
      }
      __builtin_amdgcn_s_setprio(1);
#pragma unroll
      for (int ks = 0; ks < 4; ++ks) {
        const char* vb = (const char*)Vs[cur] + l31 * 128 + ((ks * 32 + hi * 16) ^ sw);
#pragma unroll
        for (int dt = 0; dt < 4; ++dt) {
          bfrag vf = *(const bfrag*)(vb + dt * 4096);
          o[dt] = __builtin_amdgcn_mfma_f32_32x32x16_bf16(vf, pfr[ks], o[dt], 0, 0, 0);
        }
      }
      __builtin_amdgcn_s_setprio(0);
    }
    __syncthreads();
    if (pf) {
#pragma unroll
      for (int i = 0; i < 2; ++i) {
        *(s16x8*)((char*)Ks[cur ^ 1] + kldst[i]) = kr_[i];
        *(s16x8*)((char*)Vs[cur ^ 1] + vldst[i]) = vr_[i];
      }
    }
    __syncthreads();
  }
  const float linv = 1.f / l;
  short* aop = ao + (size_t)(b * 2048 + qg) * 4096 + h * 128 + 4 * hi;
#pragma unroll
  for (int dt = 0; dt < 4; ++dt)
#pragma unroll
    for (int r = 0; r < 16; ++r) {
      int d = dt * 32 + (r & 3) + 8 * (r >> 2);
      aop[d] = f2bf(o[dt][r] * linv);
    }
}

// ---------- launch ----------
extern "C" void kernel_launch(void* const* d_in, const int* in_sizes, int n_in,
                              void* d_out, int out_size, void* d_ws, size_t ws_size,
                              hipStream_t stream) {
  const float* x  = (const float*)d_in[0];
  const float* wq = (const float*)d_in[1];
  const float* wk = (const float*)d_in[2];
  const float* wv = (const float*)d_in[3];
  const float* wo = (const float*)d_in[4];
  const float* fc = (const float*)d_in[7];
  const float* fs = (const float*)d_in[8];

  char* ws = (char*)d_ws;
  short* xb    = (short*)(ws);                    // [4096][4096] bf16; reused as ao
  short* ao    = xb;
  short* wqkvb = (short*)(ws + 33554432ull);      // [6144][4096] bf16
  short* qkv   = (short*)(ws + 83886080ull);      // [4096][6144] bf16
  short* vt    = (short*)(ws + 134217728ull);     // [2][8][128][2048] bf16
  short* wob   = (short*)(ws + 167772160ull);     // [4096][4096] bf16

  cvt4<<<40960, 256, 0, stream>>>(x, wq, wk, wv,
                                  xb, wqkvb, wqkvb + 16777216, wqkvb + 20971520);
  gemm128n<true><<<768, 512, 0, stream>>>(xb, wqkvb, qkv, 4096, 6144, 4096, 24, fc, fs);
  vtrans<<<dim3(32, 8, 2), 256, 0, stream>>>(qkv, vt);
  cvt_f32_bf16<<<16384, 256, 0, stream>>>(wo, wob, 4194304);
  fattn2<<<dim3(8, 32, 2), 512, 0, stream>>>(qkv, vt, ao);
  gemm256p<false><<<256, 512, 0, stream>>>(ao, wob, (float*)d_out, 4096, 4096, 4096, 16);
}

// Round 15
// 478.379 us; speedup vs baseline: 1.4497x; 1.0012x over previous
//
#include <hip/hip_runtime.h>
#include <hip/hip_bf16.h>
#include <math.h>

// ---------- types ----------
typedef __attribute__((ext_vector_type(8)))  __bf16 bfrag;   // MFMA A/B operand (8 bf16)
typedef __attribute__((ext_vector_type(4)))  float  f32x4;
typedef __attribute__((ext_vector_type(16))) float  f32x16;  // 32x32 MFMA C/D
typedef __attribute__((ext_vector_type(8)))  short  s16x8;
typedef __attribute__((ext_vector_type(4)))  short  s16x4;
typedef __attribute__((ext_vector_type(2)))  unsigned u32x2;
typedef __attribute__((ext_vector_type(4)))  unsigned u32x4;

__device__ __forceinline__ short f2bf(float f) {
  return (short)__builtin_bit_cast(unsigned short, (__bf16)f);
}
__device__ __forceinline__ float bf2f(short s) {
  return (float)__builtin_bit_cast(__bf16, (unsigned short)s);
}
__device__ __forceinline__ unsigned cvtpk(float lo, float hi_) {
  unsigned r;
  asm("v_cvt_pk_bf16_f32 %0, %1, %2" : "=v"(r) : "v"(lo), "v"(hi_));
  return r;
}
__device__ __forceinline__ void gll16(const void* g, void* l) {
  __builtin_amdgcn_global_load_lds((const __attribute__((address_space(1))) void*)g,
                                   (__attribute__((address_space(3))) void*)l, 16, 0, 0);
}

// ---------- f32 -> bf16 converts (nontemporal input reads: read-once data) ----------
__global__ __launch_bounds__(256) void cvt_f32_bf16(const float* __restrict__ in,
                                                    short* __restrict__ out, int n4) {
  int i = blockIdx.x * 256 + threadIdx.x;
  if (i >= n4) return;
  f32x4 v = __builtin_nontemporal_load((const f32x4*)in + i);
  s16x4 o;
  o.x = f2bf(v.x); o.y = f2bf(v.y); o.z = f2bf(v.z); o.w = f2bf(v.w);
  ((s16x4*)out)[i] = o;
}

__global__ __launch_bounds__(256) void cvt4(const float* __restrict__ x,
                                            const float* __restrict__ wq,
                                            const float* __restrict__ wk,
                                            const float* __restrict__ wv,
                                            short* __restrict__ xb,
                                            short* __restrict__ wqb,
                                            short* __restrict__ wkb,
                                            short* __restrict__ wvb) {
  const int b = blockIdx.x;
  const float* in; short* out; int base;
  if (b < 16384)      { in = x;  out = xb;  base = 0; }
  else if (b < 32768) { in = wq; out = wqb; base = 16384 * 256; }
  else if (b < 36864) { in = wk; out = wkb; base = 32768 * 256; }
  else                { in = wv; out = wvb; base = 36864 * 256; }
  const int idx = b * 256 + threadIdx.x - base;
  f32x4 v = __builtin_nontemporal_load((const f32x4*)in + idx);
  s16x4 o;
  o.x = f2bf(v.x); o.y = f2bf(v.y); o.z = f2bf(v.z); o.w = f2bf(v.w);
  ((s16x4*)out)[idx] = o;
}

// ---------- shared staging macro (half-tile = 128 rows x 64 cols, 2 gll16/thr) ----------
#define STG_(OP, OPs, boff, bb, hh, kt_, Kd)                                     \
  do {                                                                           \
    _Pragma("unroll")                                                            \
    for (int s = 0; s < 2; ++s)                                                  \
      gll16(OP + (size_t)(boff + (hh) * 128 + s * 64 + r0) * Kd + (kt_) * 64 + csrc * 8, \
            (char*)OPs[bb] + ((hh) * 128 + s * 64 + wid * 8) * 128);             \
  } while (0)

// ---------- GEMM 128x256 (QKV; 768 blocks) + fused RoPE + fused V-transpose ----------
// Q/K blocks (bn<5120): RoPE in epilogue (pairs in lanes lr, lr^1).
// V blocks (bn>=5120): write acc DIRECTLY TRANSPOSED to vt[b][kvh][d][s]
// (4 consecutive tokens per s16x4 store); qkv V-region never written; vtrans gone.
template<bool ROPE>
__global__ __launch_bounds__(512) void gemm128n(const short* __restrict__ A,
                                                const short* __restrict__ B,
                                                short* __restrict__ C,
                                                short* __restrict__ vt,
                                                int M, int N, int K, int NBX,
                                                const float* __restrict__ fcos,
                                                const float* __restrict__ fsin) {
  __shared__ __align__(16) short As[2][128 * 64];
  __shared__ __align__(16) short Bs[2][256 * 64];
  const int tid = threadIdx.x, lane = tid & 63, wid = tid >> 6;
  const int lr = lane & 15, lg = lane >> 4;
  const int wm = wid >> 2, wn = wid & 3;
  const int orig = blockIdx.x;
  const int xc = orig & 7, o8 = orig >> 3;
  const int s8 = o8 >> 5, t8 = o8 & 31;
  const int bmi = ((xc >> 1) << 3) + (t8 >> 2);
  const int bni = (xc & 1) * (NBX >> 1) + (s8 << 2) + (t8 & 3);
  const int bm = bmi << 7, bn = bni << 8;
  const int NT = K >> 6;
  const int r0 = tid >> 3;
  const int c0 = tid & 7;
  const int csrc = c0 ^ (r0 & 7);

  int ch[2];
#pragma unroll
  for (int ks = 0; ks < 2; ++ks) ch[ks] = (((ks << 2) | lg) ^ (lr & 7)) << 4;
  const int aoff  = (wm * 64 + lr) * 128;
  const int boff2 = (wn * 32 + lr) * 128;

#define RD_A(dst, bb)                                                            \
  do {                                                                           \
    const char* ab = (const char*)As[bb] + aoff;                                 \
    _Pragma("unroll") for (int i = 0; i < 4; ++i)                                \
      _Pragma("unroll") for (int ks = 0; ks < 2; ++ks)                           \
        dst[i][ks] = *(const bfrag*)(ab + i * 2048 + ch[ks]);                    \
  } while (0)
#define RD_B(dst, bb, jh)                                                        \
  do {                                                                           \
    const char* bp = (const char*)Bs[bb] + boff2 + (jh) * 16384;                 \
    _Pragma("unroll") for (int j = 0; j < 2; ++j)                                \
      _Pragma("unroll") for (int ks = 0; ks < 2; ++ks)                           \
        dst[j][ks] = *(const bfrag*)(bp + j * 2048 + ch[ks]);                    \
  } while (0)
#define MFMA16(af, bf, jh)                                                       \
  do {                                                                           \
    __builtin_amdgcn_s_setprio(1);                                               \
    _Pragma("unroll") for (int ks = 0; ks < 2; ++ks)                             \
      _Pragma("unroll") for (int i = 0; i < 4; ++i)                              \
        _Pragma("unroll") for (int j = 0; j < 2; ++j)                            \
          acc[i][(jh) * 2 + j] = __builtin_amdgcn_mfma_f32_16x16x32_bf16(        \
              af[i][ks], bf[j][ks], acc[i][(jh) * 2 + j], 0, 0, 0);              \
    __builtin_amdgcn_s_setprio(0);                                               \
  } while (0)

  STG_(A, As, bm, 0, 0, 0, K);
  STG_(B, Bs, bn, 0, 0, 0, K);
  STG_(B, Bs, bn, 0, 1, 0, K);
  if (NT > 1) {
    STG_(A, As, bm, 1, 0, 1, K);
    STG_(B, Bs, bn, 1, 0, 1, K);
    asm volatile("s_waitcnt vmcnt(4)" ::: "memory");
  } else {
    asm volatile("s_waitcnt vmcnt(0)" ::: "memory");
  }
  __builtin_amdgcn_s_barrier();
  __builtin_amdgcn_sched_barrier(0);

  f32x4 acc[4][4] = {};
  bfrag a_[4][2], b_lo[2][2], b_hi[2][2];

  for (int kt = 0; kt < NT; ++kt) {
    const int b = kt & 1;
    RD_A(a_, b);
    RD_B(b_lo, b, 0);
    if (kt + 1 < NT) STG_(B, Bs, bn, b ^ 1, 1, kt + 1, K);
    MFMA16(a_, b_lo, 0);
    __builtin_amdgcn_s_barrier();
    __builtin_amdgcn_sched_barrier(0);
    RD_B(b_hi, b, 1);
    if (kt + 2 < NT) {
      STG_(A, As, bm, b, 0, kt + 2, K);
      STG_(B, Bs, bn, b, 0, kt + 2, K);
    }
    MFMA16(a_, b_hi, 1);
    if (kt + 1 < NT) {
      if (kt + 2 < NT) asm volatile("s_waitcnt vmcnt(4)" ::: "memory");
      else             asm volatile("s_waitcnt vmcnt(0)" ::: "memory");
      __builtin_amdgcn_s_barrier();
      __builtin_amdgcn_sched_barrier(0);
    }
  }
#undef RD_A
#undef RD_B
#undef MFMA16
  // ---- epilogue: RoPE (Q/K) | transposed-V | plain ----
  const int rb = bm + wm * 64 + lg * 4, cb = bn + wn * 32 + lr;
  if (ROPE && bn < 5120) {
    const bool odd = (lr & 1) != 0;
#pragma unroll
    for (int j = 0; j < 2; ++j) {
      const int iidx = (wn * 32 + j * 16 + lr) >> 1;
#pragma unroll
      for (int i = 0; i < 4; ++i)
#pragma unroll
        for (int r = 0; r < 4; ++r) {
          const int row = rb + i * 16 + r;
          const int sp = row & 2047;
          const float c  = fcos[sp * 64 + iidx];
          const float sn = fsin[sp * 64 + iidx];
#pragma unroll
          for (int jh = 0; jh < 2; ++jh) {
            float own = acc[i][jh * 2 + j][r];
            float par = __shfl_xor(own, 1, 64);
            float out = odd ? (par * sn + own * c) : (own * c - par * sn);
            C[(size_t)row * N + (cb + jh * 128 + j * 16)] = f2bf(out);
          }
        }
    }
  } else if (ROPE) {
    // V block: write transposed into vt[b][kvh][d][2048]; skip qkv write.
#pragma unroll
    for (int jh = 0; jh < 2; ++jh)
#pragma unroll
      for (int j = 0; j < 2; ++j) {
        const int vcol = cb + jh * 128 + j * 16 - 5120;   // 0..1023
        const int kvh = vcol >> 7, d = vcol & 127;
#pragma unroll
        for (int i = 0; i < 4; ++i) {
          const int row0 = rb + i * 16;                   // 4 consecutive tokens
          const int bb = row0 >> 11, s0 = row0 & 2047;
          s16x4 v;
#pragma unroll
          for (int r = 0; r < 4; ++r) v[r] = f2bf(acc[i][jh * 2 + j][r]);
          *(s16x4*)(vt + (size_t)((bb * 8 + kvh) * 128 + d) * 2048 + s0) = v;
        }
      }
  } else {
#pragma unroll
    for (int i = 0; i < 4; ++i)
#pragma unroll
      for (int jh = 0; jh < 2; ++jh)
#pragma unroll
        for (int j = 0; j < 2; ++j)
#pragma unroll
          for (int r = 0; r < 4; ++r)
            C[(size_t)(rb + i * 16 + r) * N + (cb + jh * 128 + j * 16)] =
                f2bf(acc[i][jh * 2 + j][r]);
  }
}

// ---------- GEMM 256x256, BK=64, m201 8-phase (out-proj; 256 blocks) ----------
template<bool BF16OUT>
__global__ __launch_bounds__(512) void gemm256p(const short* __restrict__ A,
                                                const short* __restrict__ B,
                                                void* __restrict__ Cv,
                                                int M, int N, int K, int NBX) {
  __shared__ __align__(16) short As[2][256 * 64];   // 64 KB
  __shared__ __align__(16) short Bs[2][256 * 64];   // 64 KB
  const int tid = threadIdx.x, lane = tid & 63, wid = tid >> 6;
  const int lr = lane & 15, lg = lane >> 4;
  const int wm = wid >> 2, wn = wid & 3;
  const int orig = blockIdx.x;
  const int xc = orig & 7, o8 = orig >> 3;
  const int bmi = ((xc >> 1) << 2) + (o8 & 3);
  const int bni = (xc & 1) * (NBX >> 1) + (o8 >> 2);
  const int bm = bmi << 8, bn = bni << 8;
  const int NT = K >> 6;
  const int r0 = tid >> 3;
  const int c0 = tid & 7;
  const int csrc = c0 ^ (r0 & 7);

  int ch[2];
#pragma unroll
  for (int ks = 0; ks < 2; ++ks) ch[ks] = (((ks << 2) | lg) ^ (lr & 7)) << 4;
  const int aoff = (wm * 128 + lr) * 128;
  const int boff = (wn * 64 + lr) * 128;

#define RD_A8(dst, bb, ih)                                                       \
  do {                                                                           \
    const char* ab = (const char*)As[bb] + aoff + (ih) * 8192;                   \
    _Pragma("unroll") for (int i = 0; i < 4; ++i)                                \
      _Pragma("unroll") for (int ks = 0; ks < 2; ++ks)                           \
        dst[i][ks] = *(const bfrag*)(ab + i * 2048 + ch[ks]);                    \
  } while (0)
#define RD_B4(dst, bb, jh)                                                       \
  do {                                                                           \
    const char* bp = (const char*)Bs[bb] + boff + (jh) * 4096;                   \
    _Pragma("unroll") for (int j = 0; j < 2; ++j)                                \
      _Pragma("unroll") for (int ks = 0; ks < 2; ++ks)                           \
        dst[j][ks] = *(const bfrag*)(bp + j * 2048 + ch[ks]);                    \
  } while (0)
#define QUAD(af, bf, ih, jh)                                                     \
  do {                                                                           \
    __builtin_amdgcn_s_setprio(1);                                               \
    _Pragma("unroll") for (int ks = 0; ks < 2; ++ks)                             \
      _Pragma("unroll") for (int i = 0; i < 4; ++i)                              \
        _Pragma("unroll") for (int j = 0; j < 2; ++j)                            \
          acc[(ih) * 4 + i][(jh) * 2 + j] = __builtin_amdgcn_mfma_f32_16x16x32_bf16( \
              af[i][ks], bf[j][ks], acc[(ih) * 4 + i][(jh) * 2 + j], 0, 0, 0);   \
    __builtin_amdgcn_s_setprio(0);                                               \
  } while (0)
#define BARRIER() do { __builtin_amdgcn_s_barrier(); __builtin_amdgcn_sched_barrier(0); } while (0)

  STG_(A, As, bm, 0, 0, 0, K); STG_(A, As, bm, 0, 1, 0, K);
  STG_(B, Bs, bn, 0, 0, 0, K); STG_(B, Bs, bn, 0, 1, 0, K);
  STG_(B, Bs, bn, 1, 0, 1, K); STG_(B, Bs, bn, 1, 1, 1, K);
  asm volatile("s_waitcnt vmcnt(4)" ::: "memory");
  BARRIER();

  f32x4 acc[8][4] = {};
  bfrag a_[4][2], b_lo[2][2], b_hi[2][2];
  const int NI = NT >> 1;

  for (int it = 0; it < NI; ++it) {
    const int O  = 2 * it + 1;
    int E2 = 2 * it + 2; if (E2 >= NT) E2 = 0;
    int O2 = 2 * it + 3; if (O2 >= NT) O2 = 0;
    RD_A8(a_, 0, 0);
    RD_B4(b_lo, 0, 0);
    STG_(A, As, bm, 1, 0, O, K);
    BARRIER();
    asm volatile("s_waitcnt lgkmcnt(0)" ::: "memory");
    QUAD(a_, b_lo, 0, 0);
    BARRIER();
    RD_B4(b_hi, 0, 1);
    STG_(A, As, bm, 1, 1, O, K);
    BARRIER();
    asm volatile("s_waitcnt lgkmcnt(0)" ::: "memory");
    QUAD(a_, b_hi, 0, 1);
    BARRIER();
    RD_A8(a_, 0, 1);
    STG_(B, Bs, bn, 0, 0, E2, K);
    BARRIER();
    asm volatile("s_waitcnt lgkmcnt(0)" ::: "memory");
    QUAD(a_, b_hi, 1, 1);
    BARRIER();
    STG_(B, Bs, bn, 0, 1, E2, K);
    asm volatile("s_waitcnt vmcnt(4)" ::: "memory");
    BARRIER();
    QUAD(a_, b_lo, 1, 0);
    BARRIER();
    RD_A8(a_, 1, 0);
    RD_B4(b_lo, 1, 0);
    STG_(A, As, bm, 0, 0, E2, K);
    BARRIER();
    asm volatile("s_waitcnt lgkmcnt(0)" ::: "memory");
    QUAD(a_, b_lo, 0, 0);
    BARRIER();
    RD_B4(b_hi, 1, 1);
    STG_(A, As, bm, 0, 1, E2, K);
    BARRIER();
    asm volatile("s_waitcnt lgkmcnt(0)" ::: "memory");
    QUAD(a_, b_hi, 0, 1);
    BARRIER();
    RD_A8(a_, 1, 1);
    STG_(B, Bs, bn, 1, 0, O2, K);
    BARRIER();
    asm volatile("s_waitcnt lgkmcnt(0)" ::: "memory");
    QUAD(a_, b_hi, 1, 1);
    BARRIER();
    STG_(B, Bs, bn, 1, 1, O2, K);
    asm volatile("s_waitcnt vmcnt(4)" ::: "memory");
    BARRIER();
    QUAD(a_, b_lo, 1, 0);
    BARRIER();
  }
#undef RD_A8
#undef RD_B4
#undef QUAD
#undef BARRIER
  const int rb = bm + wm * 128 + lg * 4, cb = bn + wn * 64 + lr;
#pragma unroll
  for (int i = 0; i < 8; ++i)
#pragma unroll
    for (int j = 0; j < 4; ++j)
#pragma unroll
      for (int r = 0; r < 4; ++r) {
        size_t idx = (size_t)(rb + i * 16 + r) * N + (cb + j * 16);
        if (BF16OUT) ((short*)Cv)[idx] = f2bf(acc[i][j][r]);
        else         ((float*)Cv)[idx] = acc[i][j][r];
      }
}

// ---------- Flash attention, m214 structure; qb<->z balance flip ----------
__global__ __launch_bounds__(512, 2) void fattn2(const short* __restrict__ qkv,
                                                 const short* __restrict__ vt,
                                                 short* __restrict__ ao) {
  const int b = blockIdx.z, h = blockIdx.y;
  const int qb = b ? (int)gridDim.x - 1 - blockIdx.x : blockIdx.x;
  const int kvh = h >> 2;
  const int tid = threadIdx.x;
  const int lane = tid & 63, wid = tid >> 6;
  const int l31 = lane & 31, hi = lane >> 5;
  __shared__ __align__(16) short Ks[2][64 * 128];
  __shared__ __align__(16) short Vs[2][128 * 64];

  const int q0w   = qb * 256 + wid * 32;
  const int qg    = q0w + l31;
  const int tmaxw = q0w >> 6;
  const int NT    = 4 * qb + 4;

  bfrag qf[8];
  {
    const short* qp = qkv + (size_t)(b * 2048 + qg) * 6144 + h * 128 + hi * 8;
#pragma unroll
    for (int kk = 0; kk < 8; ++kk) qf[kk] = *(const bfrag*)(qp + kk * 16);
  }

  const int kr0 = tid >> 4, kcc = tid & 15;
  const int vd0 = tid >> 3, vkc = tid & 7;
  const int kro[2] = { kr0, kr0 + 32 };
  const int vdo[2] = { vd0, vd0 + 64 };
  int kldst[2], vldst[2];
#pragma unroll
  for (int i = 0; i < 2; ++i) {
    kldst[i] = (kro[i] * 256 + kcc * 16) ^ ((kro[i] & 7) << 4);
    vldst[i] = (vdo[i] * 128 + vkc * 16) ^ ((vdo[i] & 7) << 4);
  }
  const short* base_k = qkv + (size_t)(b * 2048) * 6144 + 4096 + kvh * 128;
  const short* base_v = vt + (size_t)((b * 8 + kvh) * 128) * 2048;

  {
    s16x8 kr_[2], vr_[2];
#pragma unroll
    for (int i = 0; i < 2; ++i) {
      kr_[i] = *(const s16x8*)(base_k + (size_t)kro[i] * 6144 + kcc * 8);
      vr_[i] = *(const s16x8*)(base_v + (size_t)vdo[i] * 2048 + vkc * 8);
    }
#pragma unroll
    for (int i = 0; i < 2; ++i) {
      *(s16x8*)((char*)Ks[0] + kldst[i]) = kr_[i];
      *(s16x8*)((char*)Vs[0] + vldst[i]) = vr_[i];
    }
  }
  __syncthreads();

  f32x16 o[4] = {};
  float m = -3.0e38f, l = 0.f;
  const float c0 = 0.08838834764831845f * 1.4426950408889634f;
  const int  sw = (l31 & 7) << 4;

  for (int t = 0; t < NT; ++t) {
    const int cur = t & 1;
    s16x8 kr_[2], vr_[2];
    const bool pf = (t + 1 < NT);
    if (pf) {
#pragma unroll
      for (int i = 0; i < 2; ++i) {
        kr_[i] = *(const s16x8*)(base_k + (size_t)((t + 1) * 64 + kro[i]) * 6144 + kcc * 8);
        vr_[i] = *(const s16x8*)(base_v + (size_t)vdo[i] * 2048 + (t + 1) * 64 + vkc * 8);
      }
    }
    if (t <= tmaxw) {
      f32x16 st[2] = {};
      {
        const char* kb = (const char*)Ks[cur] + l31 * 256;
        __builtin_amdgcn_s_setprio(1);
#pragma unroll
        for (int kk = 0; kk < 8; ++kk) {
          const int ko = (kk * 32 + hi * 16) ^ sw;
          bfrag kf0 = *(const bfrag*)(kb + ko);
          bfrag kf1 = *(const bfrag*)(kb + 8192 + ko);
          st[0] = __builtin_amdgcn_mfma_f32_32x32x16_bf16(kf0, qf[kk], st[0], 0, 0, 0);
          st[1] = __builtin_amdgcn_mfma_f32_32x32x16_bf16(kf1, qf[kk], st[1], 0, 0, 0);
        }
        __builtin_amdgcn_s_setprio(0);
      }
      if (t == tmaxw) {
        const int kb0 = t * 64 + 4 * hi;
#pragma unroll
        for (int kt = 0; kt < 2; ++kt)
#pragma unroll
          for (int r = 0; r < 16; ++r) {
            int k = kb0 + kt * 32 + (r & 3) + 8 * (r >> 2);
            if (k > qg) st[kt][r] = -3.0e38f;
          }
      }
      float mt = -3.0e38f;
#pragma unroll
      for (int kt = 0; kt < 2; ++kt)
#pragma unroll
        for (int r = 0; r < 16; ++r) mt = fmaxf(mt, st[kt][r]);
      mt = fmaxf(mt, __shfl_xor(mt, 32, 64));
      if (!__all((mt - m) * c0 <= 8.0f)) {
        float nm = fmaxf(m, mt);
        float fe = exp2f((m - nm) * c0);
        m = nm;
        l *= fe;
#pragma unroll
        for (int dt = 0; dt < 4; ++dt)
#pragma unroll
          for (int r = 0; r < 16; ++r) o[dt][r] *= fe;
      }
      const float mc = m * c0;
      float ps = 0.f;
#pragma unroll
      for (int kt = 0; kt < 2; ++kt)
#pragma unroll
        for (int r = 0; r < 16; ++r) {
          float p = exp2f(st[kt][r] * c0 - mc);
          st[kt][r] = p;
          ps += p;
        }
      ps += __shfl_xor(ps, 32, 64);
      l += ps;
      bfrag pfr[4];
#pragma unroll
      for (int kt = 0; kt < 2; ++kt) {
        u32x2 a0 = __builtin_amdgcn_permlane32_swap(cvtpk(st[kt][0],  st[kt][1]),
                                                    cvtpk(st[kt][4],  st[kt][5]),  0, 0);
        u32x2 a1 = __builtin_amdgcn_permlane32_swap(cvtpk(st[kt][2],  st[kt][3]),
                                                    cvtpk(st[kt][6],  st[kt][7]),  0, 0);
        u32x2 b0 = __builtin_amdgcn_permlane32_swap(cvtpk(st[kt][8],  st[kt][9]),
                                                    cvtpk(st[kt][12], st[kt][13]), 0, 0);
        u32x2 b1 = __builtin_amdgcn_permlane32_swap(cvtpk(st[kt][10], st[kt][11]),
                                                    cvtpk(st[kt][14], st[kt][15]), 0, 0);
        u32x4 w0 = { a0.x, a1.x, a0.y, a1.y };
        u32x4 w1 = { b0.x, b1.x, b0.y, b1.y };
        pfr[kt * 2]     = __builtin_bit_cast(bfrag, w0);
        pfr[kt * 2 + 1] = __builtin_bit_cast(bfrag, w1);
      }
      __builtin_amdgcn_s_setprio(1);
#pragma unroll
      for (int ks = 0; ks < 4; ++ks) {
        const char* vb = (const char*)Vs[cur] + l31 * 128 + ((ks * 32 + hi * 16) ^ sw);
#pragma unroll
        for (int dt = 0; dt < 4; ++dt) {
          bfrag vf = *(const bfrag*)(vb + dt * 4096);
          o[dt] = __builtin_amdgcn_mfma_f32_32x32x16_bf16(vf, pfr[ks], o[dt], 0, 0, 0);
        }
      }
      __builtin_amdgcn_s_setprio(0);
    }
    __syncthreads();
    if (pf) {
#pragma unroll
      for (int i = 0; i < 2; ++i) {
        *(s16x8*)((char*)Ks[cur ^ 1] + kldst[i]) = kr_[i];
        *(s16x8*)((char*)Vs[cur ^ 1] + vldst[i]) = vr_[i];
      }
    }
    __syncthreads();
  }
  const float linv = 1.f / l;
  short* aop = ao + (size_t)(b * 2048 + qg) * 4096 + h * 128 + 4 * hi;
#pragma unroll
  for (int dt = 0; dt < 4; ++dt)
#pragma unroll
    for (int r = 0; r < 16; ++r) {
      int d = dt * 32 + (r & 3) + 8 * (r >> 2);
      aop[d] = f2bf(o[dt][r] * linv);
    }
}

// ---------- launch ----------
extern "C" void kernel_launch(void* const* d_in, const int* in_sizes, int n_in,
                              void* d_out, int out_size, void* d_ws, size_t ws_size,
                              hipStream_t stream) {
  const float* x  = (const float*)d_in[0];
  const float* wq = (const float*)d_in[1];
  const float* wk = (const float*)d_in[2];
  const float* wv = (const float*)d_in[3];
  const float* wo = (const float*)d_in[4];
  const float* fc = (const float*)d_in[7];
  const float* fs = (const float*)d_in[8];

  char* ws = (char*)d_ws;
  short* xb    = (short*)(ws);                    // [4096][4096] bf16; reused as ao
  short* ao    = xb;
  short* wqkvb = (short*)(ws + 33554432ull);      // [6144][4096] bf16
  short* qkv   = (short*)(ws + 83886080ull);      // [4096][6144] bf16 (V region unused)
  short* vt    = (short*)(ws + 134217728ull);     // [2][8][128][2048] bf16
  short* wob   = (short*)(ws + 167772160ull);     // [4096][4096] bf16

  cvt4<<<40960, 256, 0, stream>>>(x, wq, wk, wv,
                                  xb, wqkvb, wqkvb + 16777216, wqkvb + 20971520);
  gemm128n<true><<<768, 512, 0, stream>>>(xb, wqkvb, qkv, vt,
                                          4096, 6144, 4096, 24, fc, fs);
  cvt_f32_bf16<<<16384, 256, 0, stream>>>(wo, wob, 4194304);
  fattn2<<<dim3(8, 32, 2), 512, 0, stream>>>(qkv, vt, ao);
  gemm256p<false><<<256, 512, 0, stream>>>(ao, wob, (float*)d_out, 4096, 4096, 4096, 16);
}